// Round 2
// baseline (2079.919 us; speedup 1.0000x reference)
//
#include <hip/hip_runtime.h>
#include <hip/hip_bf16.h>
#include <math.h>

// Problem constants
#define BB 4
#define SS 4096
#define DM 1024
#define HH 16
#define HD 64
#define NTOK (BB * SS)          // 16384 rows
#define TSZ ((size_t)NTOK * DM) // 16777216 floats per activation buffer

// ---------------------------------------------------------------------------
// GEMM: C[M,N] = A[M,K] @ W[N,K]^T + bias[N]   (fp32, NT layout)
// 128x128 tile, BK=16, 256 threads, 8x8 micro-tile per thread.
// ---------------------------------------------------------------------------
#define GBM 128
#define GBN 128
#define GBK 16

__global__ __launch_bounds__(256) void gemm_nt_bias(
    const float* __restrict__ A, const float* __restrict__ W,
    const float* __restrict__ bias, float* __restrict__ C,
    int M, int N, int K) {
  __shared__ float As[GBK][GBM + 4];
  __shared__ float Bs[GBK][GBN + 4];

  const int t = threadIdx.x;
  const int bm = blockIdx.y * GBM;
  const int bn = blockIdx.x * GBN;
  const int tx = t & 15;        // 0..15 -> N micro
  const int ty = t >> 4;        // 0..15 -> M micro
  const int lr = t >> 2;        // 0..63 load row
  const int lc = (t & 3) * 4;   // 0,4,8,12 load k-col

  float acc[8][8];
#pragma unroll
  for (int i = 0; i < 8; ++i)
#pragma unroll
    for (int j = 0; j < 8; ++j) acc[i][j] = 0.f;

  const float* Ar0 = A + (size_t)(bm + lr) * K + lc;
  const float* Ar1 = A + (size_t)(bm + lr + 64) * K + lc;
  const float* Wr0 = W + (size_t)(bn + lr) * K + lc;
  const float* Wr1 = W + (size_t)(bn + lr + 64) * K + lc;

  for (int k0 = 0; k0 < K; k0 += GBK) {
    float4 a0 = *(const float4*)(Ar0 + k0);
    float4 a1 = *(const float4*)(Ar1 + k0);
    float4 w0 = *(const float4*)(Wr0 + k0);
    float4 w1 = *(const float4*)(Wr1 + k0);
    __syncthreads();
    As[lc + 0][lr] = a0.x; As[lc + 1][lr] = a0.y;
    As[lc + 2][lr] = a0.z; As[lc + 3][lr] = a0.w;
    As[lc + 0][lr + 64] = a1.x; As[lc + 1][lr + 64] = a1.y;
    As[lc + 2][lr + 64] = a1.z; As[lc + 3][lr + 64] = a1.w;
    Bs[lc + 0][lr] = w0.x; Bs[lc + 1][lr] = w0.y;
    Bs[lc + 2][lr] = w0.z; Bs[lc + 3][lr] = w0.w;
    Bs[lc + 0][lr + 64] = w1.x; Bs[lc + 1][lr + 64] = w1.y;
    Bs[lc + 2][lr + 64] = w1.z; Bs[lc + 3][lr + 64] = w1.w;
    __syncthreads();
#pragma unroll
    for (int kk = 0; kk < GBK; ++kk) {
      float a[8], b[8];
      *(float4*)&a[0] = *(const float4*)&As[kk][ty * 8];
      *(float4*)&a[4] = *(const float4*)&As[kk][ty * 8 + 4];
      *(float4*)&b[0] = *(const float4*)&Bs[kk][tx * 8];
      *(float4*)&b[4] = *(const float4*)&Bs[kk][tx * 8 + 4];
#pragma unroll
      for (int i = 0; i < 8; ++i)
#pragma unroll
        for (int j = 0; j < 8; ++j)
          acc[i][j] = fmaf(a[i], b[j], acc[i][j]);
    }
  }

  float bo[8];
#pragma unroll
  for (int j = 0; j < 8; ++j) bo[j] = bias[bn + tx * 8 + j];
#pragma unroll
  for (int i = 0; i < 8; ++i) {
    const size_t row = (size_t)(bm + ty * 8 + i);
    float4 o0 = make_float4(acc[i][0] + bo[0], acc[i][1] + bo[1],
                            acc[i][2] + bo[2], acc[i][3] + bo[3]);
    float4 o1 = make_float4(acc[i][4] + bo[4], acc[i][5] + bo[5],
                            acc[i][6] + bo[6], acc[i][7] + bo[7]);
    *(float4*)&C[row * N + bn + tx * 8] = o0;
    *(float4*)&C[row * N + bn + tx * 8 + 4] = o1;
  }
}

// ---------------------------------------------------------------------------
// Halo snapshot: save original rows (s0-2, s0-1) for every 128-row chunk so
// the conv can then run IN-PLACE. H layout: [b][z][2][DM]. X1/H1 optional.
// ---------------------------------------------------------------------------
__global__ __launch_bounds__(256) void halo_save2(
    const float* __restrict__ X0, float* __restrict__ H0,
    const float* __restrict__ X1, float* __restrict__ H1) {
  const int z = blockIdx.x, b = blockIdx.y, t = threadIdx.x;
  const int s0 = z * 128;
  const size_t base = (size_t)b * SS * DM;
  float* h0 = H0 + (size_t)(b * 32 + z) * 2 * DM;
  for (int c = t; c < DM; c += 256) {
    h0[c]      = (s0 >= 2) ? X0[base + (size_t)(s0 - 2) * DM + c] : 0.f;
    h0[DM + c] = (s0 >= 1) ? X0[base + (size_t)(s0 - 1) * DM + c] : 0.f;
  }
  if (X1 != nullptr) {
    float* h1 = H1 + (size_t)(b * 32 + z) * 2 * DM;
    for (int c = t; c < DM; c += 256) {
      h1[c]      = (s0 >= 2) ? X1[base + (size_t)(s0 - 2) * DM + c] : 0.f;
      h1[DM + c] = (s0 >= 1) ? X1[base + (size_t)(s0 - 1) * DM + c] : 0.f;
    }
  }
}

// ---------------------------------------------------------------------------
// In-place depthwise causal conv (KS=3) along s; weight indexed d = c & 63.
// Each thread owns one (b,c) column of a 128-row chunk; window carried in
// registers; chunk-boundary history comes from the halo snapshot.
// ---------------------------------------------------------------------------
__global__ __launch_bounds__(256) void dwconv_ip(
    float* __restrict__ X, const float* __restrict__ halo,
    const float* __restrict__ w, const float* __restrict__ bias,
    int apply_fm) {
  const int c = blockIdx.x * 256 + threadIdx.x;  // channel 0..1023
  const int b = blockIdx.y;
  const int z = blockIdx.z;
  const int s0 = z * 128;
  const int d = c & 63;
  const float w0 = w[d * 3 + 0], w1 = w[d * 3 + 1], w2 = w[d * 3 + 2];
  const float bb = bias[d];
  const size_t base = (size_t)b * SS * DM + c;
  const float* hp = halo + (size_t)(b * 32 + z) * 2 * DM;

  float xm2 = hp[c];
  float xm1 = hp[DM + c];
  for (int s = s0; s < s0 + 128; ++s) {
    const float xc = X[base + (size_t)s * DM];
    float y = bb + w0 * xm2 + w1 * xm1 + w2 * xc;
    if (apply_fm) y = (y > 0.f) ? (y + 1.f) : expf(y);
    X[base + (size_t)s * DM] = y;
    xm2 = xm1;
    xm1 = xc;
  }
}

// ---------------------------------------------------------------------------
// Partial KV: KVp[bh][chunk][d][e] = sum_{s in chunk} K[b,s,h,d]*V[b,s,h,e]
// Ksp[bh][chunk][d] = sum K. Grid (64 bh, 8 chunks of 512). Deterministic.
// ---------------------------------------------------------------------------
__global__ __launch_bounds__(256) void kv_accum(
    const float* __restrict__ Kp, const float* __restrict__ Vp,
    float* __restrict__ KVp, float* __restrict__ Ksp) {
  const int bh = blockIdx.x;
  const int b = bh >> 4, h = bh & 15;
  const int chunk = blockIdx.y;
  const int s0 = chunk * 512;
  const int t = threadIdx.x;
  __shared__ float Ks[32][64];
  __shared__ float Vs[32][64];

  float acc[16];
#pragma unroll
  for (int j = 0; j < 16; ++j) acc[j] = 0.f;
  float ks = 0.f;
  const int d = t & 63;
  const int eg = t >> 6;  // 0..3
  const int e0 = eg * 16;
  const size_t basek = ((size_t)b * SS + s0) * DM + h * HD;

  for (int c = 0; c < 512; c += 32) {
    __syncthreads();
#pragma unroll
    for (int p = 0; p < 2; ++p) {
      const int lin = t * 4 + p * 1024;  // 0..2047
      const int sl = lin >> 6, dd = lin & 63;
      *(float4*)&Ks[sl][dd] = *(const float4*)&Kp[basek + (size_t)(c + sl) * DM + dd];
      *(float4*)&Vs[sl][dd] = *(const float4*)&Vp[basek + (size_t)(c + sl) * DM + dd];
    }
    __syncthreads();
#pragma unroll 4
    for (int ss = 0; ss < 32; ++ss) {
      const float kd = Ks[ss][d];
      if (eg == 0) ks += kd;
#pragma unroll
      for (int j = 0; j < 16; ++j)
        acc[j] = fmaf(kd, Vs[ss][e0 + j], acc[j]);
    }
  }
  float* kvp = &KVp[((size_t)bh * 8 + chunk) * 4096 + d * 64 + e0];
#pragma unroll
  for (int j = 0; j < 16; ++j) kvp[j] = acc[j];
  if (eg == 0) Ksp[(bh * 8 + chunk) * 64 + d] = ks;
}

__global__ __launch_bounds__(256) void kv_reduce(
    const float* __restrict__ KVp, const float* __restrict__ Ksp,
    float* __restrict__ KV, float* __restrict__ Ksum) {
  const int bh = blockIdx.x;
  const int t = threadIdx.x;
  for (int i = t; i < 4096; i += 256) {
    float s = 0.f;
#pragma unroll
    for (int c = 0; c < 8; ++c) s += KVp[((size_t)bh * 8 + c) * 4096 + i];
    KV[(size_t)bh * 4096 + i] = s;
  }
  if (t < 64) {
    float s = 0.f;
#pragma unroll
    for (int c = 0; c < 8; ++c) s += Ksp[(bh * 8 + c) * 64 + t];
    Ksum[bh * 64 + t] = s;
  }
}

// ---------------------------------------------------------------------------
// V_new[b,s,h,e] = Z(s) * sum_d Q[b,s,h,d] * KV[bh,d,e],
// Z = 1/(Q . (Ksum+eps)). In-place into Q buffer (rows staged to LDS first).
// Grid (64 bh, 64 s-chunks of 64 rows).
// ---------------------------------------------------------------------------
__global__ __launch_bounds__(256) void attn_apply(
    float* __restrict__ Qp, const float* __restrict__ KV,
    const float* __restrict__ Ksum) {
  const int bh = blockIdx.x;
  const int b = bh >> 4, h = bh & 15;
  const int s0 = blockIdx.y * 64;
  const int t = threadIdx.x;
  __shared__ float Qs[64][68];
  __shared__ float KVs[64][68];
  __shared__ float kse[64];
  const size_t baseq = ((size_t)b * SS + s0) * DM + h * HD;

#pragma unroll
  for (int p = 0; p < 4; ++p) {
    const int lin = t * 4 + p * 1024;  // 0..4095
    const int r = lin >> 6, dd = lin & 63;
    *(float4*)&Qs[r][dd] = *(const float4*)&Qp[baseq + (size_t)r * DM + dd];
    *(float4*)&KVs[r][dd] = *(const float4*)&KV[(size_t)bh * 4096 + lin];
  }
  if (t < 64) kse[t] = Ksum[bh * 64 + t] + 1e-6f;
  __syncthreads();

  const int r = t >> 2;       // s-row 0..63
  const int e0 = (t & 3) * 16;
  float acc[16];
#pragma unroll
  for (int j = 0; j < 16; ++j) acc[j] = 0.f;
  float den = 0.f;
#pragma unroll 8
  for (int dd = 0; dd < 64; ++dd) {
    const float qv = Qs[r][dd];
    den = fmaf(qv, kse[dd], den);
#pragma unroll
    for (int j = 0; j < 16; ++j)
      acc[j] = fmaf(qv, KVs[dd][e0 + j], acc[j]);
  }
  const float z = 1.0f / den;
  float* outp = &Qp[baseq + (size_t)r * DM + e0];
#pragma unroll
  for (int jj = 0; jj < 4; ++jj) {
    float4 o = make_float4(acc[jj * 4 + 0] * z, acc[jj * 4 + 1] * z,
                           acc[jj * 4 + 2] * z, acc[jj * 4 + 3] * z);
    *(float4*)&outp[jj * 4] = o;
  }
}

// ---------------------------------------------------------------------------
extern "C" void kernel_launch(void* const* d_in, const int* in_sizes, int n_in,
                              void* d_out, int out_size, void* d_ws, size_t ws_size,
                              hipStream_t stream) {
  const float* query = (const float*)d_in[0];
  const float* key   = (const float*)d_in[1];
  const float* value = (const float*)d_in[2];
  const float* q_w = (const float*)d_in[3];
  const float* q_b = (const float*)d_in[4];
  const float* k_w = (const float*)d_in[5];
  const float* k_b = (const float*)d_in[6];
  const float* v_w = (const float*)d_in[7];
  const float* v_b = (const float*)d_in[8];
  const float* o_w = (const float*)d_in[9];
  const float* o_b = (const float*)d_in[10];
  const float* qc_w = (const float*)d_in[11];
  const float* qc_b = (const float*)d_in[12];
  const float* kc_w = (const float*)d_in[13];
  const float* kc_b = (const float*)d_in[14];
  const float* vc_w = (const float*)d_in[15];
  const float* vc_b = (const float*)d_in[16];
  float* out = (float*)d_out;

  // Workspace layout (floats). Total ~146 MB.
  float* ws   = (float*)d_ws;
  float* buf0 = ws;                      // k proj -> conv'd K -> q proj -> conv'd Q -> attn out
  float* buf1 = ws + TSZ;                // v proj -> conv'd V
  float* KVp  = ws + 2 * TSZ;            // 64*8*4096
  float* Ksp  = KVp + (size_t)64 * 8 * 4096;   // 64*8*64
  float* KV   = Ksp + 64 * 8 * 64;       // 64*4096
  float* Ksum = KV + (size_t)64 * 4096;  // 64*64
  float* halo0 = Ksum + 64 * 64;         // 4*32*2*1024
  float* halo1 = halo0 + (size_t)4 * 32 * 2 * DM;

  const dim3 gg(DM / GBN, NTOK / GBM);    // (8,128)
  const dim3 cg(DM / 256, BB, SS / 128);  // (4,4,32)
  const dim3 hg(SS / 128, BB);            // (32,4)

  // K and V pipeline
  gemm_nt_bias<<<gg, 256, 0, stream>>>(key,   k_w, k_b, buf0, NTOK, DM, DM);
  gemm_nt_bias<<<gg, 256, 0, stream>>>(value, v_w, v_b, buf1, NTOK, DM, DM);
  halo_save2<<<hg, 256, 0, stream>>>(buf0, halo0, buf1, halo1);
  dwconv_ip<<<cg, 256, 0, stream>>>(buf0, halo0, kc_w, kc_b, 1);  // K (feature map)
  dwconv_ip<<<cg, 256, 0, stream>>>(buf1, halo1, vc_w, vc_b, 0);  // V
  kv_accum<<<dim3(64, 8), 256, 0, stream>>>(buf0, buf1, KVp, Ksp);
  kv_reduce<<<64, 256, 0, stream>>>(KVp, Ksp, KV, Ksum);

  // Q pipeline (reuses buf0 after KV is built; stream ordering guarantees it)
  gemm_nt_bias<<<gg, 256, 0, stream>>>(query, q_w, q_b, buf0, NTOK, DM, DM);
  halo_save2<<<hg, 256, 0, stream>>>(buf0, halo0, nullptr, nullptr);
  dwconv_ip<<<cg, 256, 0, stream>>>(buf0, halo0, qc_w, qc_b, 1);  // Q (feature map)
  attn_apply<<<dim3(64, 64), 256, 0, stream>>>(buf0, KV, Ksum);

  // Output projection
  gemm_nt_bias<<<gg, 256, 0, stream>>>(buf0, o_w, o_b, out, NTOK, DM, DM);
}

// Round 3
// 941.268 us; speedup vs baseline: 2.2097x; 2.2097x over previous
//
#include <hip/hip_runtime.h>
#include <hip/hip_bf16.h>
#include <math.h>

// Problem constants
#define BB 4
#define SS 4096
#define DM 1024
#define HH 16
#define HD 64
#define NTOK (BB * SS)          // 16384 rows
#define TSZ ((size_t)NTOK * DM) // 16777216 elements per activation plane

typedef _Float16 half8 __attribute__((ext_vector_type(8)));
typedef _Float16 half4v __attribute__((ext_vector_type(4)));
typedef float floatx4 __attribute__((ext_vector_type(4)));

__device__ __forceinline__ void gload16(const void* g, void* l) {
  __builtin_amdgcn_global_load_lds(
      (const __attribute__((address_space(1))) void*)g,
      (__attribute__((address_space(3))) void*)l, 16, 0, 0);
}

// ---------------------------------------------------------------------------
// Split fp32 -> (hi, lo) f16 planes.  x = hi + lo + O(2^-22 |x|).
// ---------------------------------------------------------------------------
__global__ __launch_bounds__(256) void split_f32(
    const float* __restrict__ X, _Float16* __restrict__ hi,
    _Float16* __restrict__ lo, int n4) {
  const int i = blockIdx.x * 256 + threadIdx.x;
  if (i >= n4) return;
  const float4 x = ((const float4*)X)[i];
  half4v h, l;
  h.x = (_Float16)x.x; l.x = (_Float16)(x.x - (float)h.x);
  h.y = (_Float16)x.y; l.y = (_Float16)(x.y - (float)h.y);
  h.z = (_Float16)x.z; l.z = (_Float16)(x.z - (float)h.z);
  h.w = (_Float16)x.w; l.w = (_Float16)(x.w - (float)h.w);
  ((half4v*)hi)[i] = h;
  ((half4v*)lo)[i] = l;
}

// ---------------------------------------------------------------------------
// Split-precision MFMA GEMM:  C[M,N] = A[M,K] @ W[N,K]^T + bias
// A,W given as (hi,lo) f16 planes. 128x128 tile, BK=32, 256 threads (4 waves),
// each wave 4x4 tiles of 16x16x32 MFMA; 3 MFMA per (hi/lo) product pair.
// global_load_lds (16B) staging; natural row-major LDS layout (bank-uniform
// for the 16x16x32 fragment read pattern).
// ---------------------------------------------------------------------------
__global__ __launch_bounds__(256) void gemm_split_nt(
    const _Float16* __restrict__ Ahi, const _Float16* __restrict__ Alo,
    const _Float16* __restrict__ Whi, const _Float16* __restrict__ Wlo,
    const float* __restrict__ bias, float* __restrict__ C,
    int M, int N, int K) {
  __shared__ _Float16 sAh[128 * 32];
  __shared__ _Float16 sAl[128 * 32];
  __shared__ _Float16 sBh[128 * 32];
  __shared__ _Float16 sBl[128 * 32];

  const int t = threadIdx.x;
  const int w = t >> 6, lane = t & 63;
  const int bm = blockIdx.y * 128, bn = blockIdx.x * 128;
  const int mbase = (w & 1) * 64, nbase = (w >> 1) * 64;
  const int fm = lane & 15;            // fragment row (m or n)
  const int fk = (lane >> 4) * 8;      // fragment k-offset

  floatx4 acc[4][4];
#pragma unroll
  for (int i = 0; i < 4; ++i)
#pragma unroll
    for (int j = 0; j < 4; ++j) acc[i][j] = (floatx4){0.f, 0.f, 0.f, 0.f};

  // Staging: tile = 128 rows x 32 k = 512 chunks of 16B per plane.
  // Thread t covers chunks t and t+256. LDS dest base is wave-uniform.
  const int r0 = t >> 2, g0 = (t & 3) * 8;
  const int r1 = (t + 256) >> 2, g1 = (t & 3) * 8;  // (t+256)&3 == t&3
  const int lo0 = (w * 64) * 8;                     // f16 elem offset, j=0
  const int lo1 = (256 + w * 64) * 8;               // j=1

  const _Float16* pAh0 = Ahi + (size_t)(bm + r0) * K + g0;
  const _Float16* pAh1 = Ahi + (size_t)(bm + r1) * K + g1;
  const _Float16* pAl0 = Alo + (size_t)(bm + r0) * K + g0;
  const _Float16* pAl1 = Alo + (size_t)(bm + r1) * K + g1;
  const _Float16* pBh0 = Whi + (size_t)(bn + r0) * K + g0;
  const _Float16* pBh1 = Whi + (size_t)(bn + r1) * K + g1;
  const _Float16* pBl0 = Wlo + (size_t)(bn + r0) * K + g0;
  const _Float16* pBl1 = Wlo + (size_t)(bn + r1) * K + g1;

  for (int k0 = 0; k0 < K; k0 += 32) {
    __syncthreads();
    gload16(pAh0 + k0, &sAh[lo0]);
    gload16(pAh1 + k0, &sAh[lo1]);
    gload16(pAl0 + k0, &sAl[lo0]);
    gload16(pAl1 + k0, &sAl[lo1]);
    gload16(pBh0 + k0, &sBh[lo0]);
    gload16(pBh1 + k0, &sBh[lo1]);
    gload16(pBl0 + k0, &sBl[lo0]);
    gload16(pBl1 + k0, &sBl[lo1]);
    __syncthreads();

    half8 ah[4], al[4], bh[4], bl[4];
#pragma unroll
    for (int i = 0; i < 4; ++i) {
      ah[i] = *(const half8*)&sAh[(mbase + i * 16 + fm) * 32 + fk];
      al[i] = *(const half8*)&sAl[(mbase + i * 16 + fm) * 32 + fk];
      bh[i] = *(const half8*)&sBh[(nbase + i * 16 + fm) * 32 + fk];
      bl[i] = *(const half8*)&sBl[(nbase + i * 16 + fm) * 32 + fk];
    }
#pragma unroll
    for (int i = 0; i < 4; ++i)
#pragma unroll
      for (int j = 0; j < 4; ++j) {
        acc[i][j] = __builtin_amdgcn_mfma_f32_16x16x32_f16(ah[i], bh[j], acc[i][j], 0, 0, 0);
        acc[i][j] = __builtin_amdgcn_mfma_f32_16x16x32_f16(ah[i], bl[j], acc[i][j], 0, 0, 0);
        acc[i][j] = __builtin_amdgcn_mfma_f32_16x16x32_f16(al[i], bh[j], acc[i][j], 0, 0, 0);
      }
  }

  // Epilogue. C/D layout: row = (lane>>4)*4 + reg (m), col = lane&15 (n).
  const int cr = (lane >> 4) * 4;
#pragma unroll
  for (int i = 0; i < 4; ++i) {
    const int grow = bm + mbase + i * 16 + cr;
#pragma unroll
    for (int j = 0; j < 4; ++j) {
      const int gcol = bn + nbase + j * 16 + fm;
      const float bo = bias[gcol];
#pragma unroll
      for (int r = 0; r < 4; ++r)
        C[(size_t)(grow + r) * N + gcol] = acc[i][j][r] + bo;
    }
  }
}

// ---------------------------------------------------------------------------
// Halo snapshot for in-place conv. H layout: [b][z][2][DM]. X1/H1 optional.
// ---------------------------------------------------------------------------
__global__ __launch_bounds__(256) void halo_save2(
    const float* __restrict__ X0, float* __restrict__ H0,
    const float* __restrict__ X1, float* __restrict__ H1) {
  const int z = blockIdx.x, b = blockIdx.y, t = threadIdx.x;
  const int s0 = z * 128;
  const size_t base = (size_t)b * SS * DM;
  float* h0 = H0 + (size_t)(b * 32 + z) * 2 * DM;
  for (int c = t; c < DM; c += 256) {
    h0[c]      = (s0 >= 2) ? X0[base + (size_t)(s0 - 2) * DM + c] : 0.f;
    h0[DM + c] = (s0 >= 1) ? X0[base + (size_t)(s0 - 1) * DM + c] : 0.f;
  }
  if (X1 != nullptr) {
    float* h1 = H1 + (size_t)(b * 32 + z) * 2 * DM;
    for (int c = t; c < DM; c += 256) {
      h1[c]      = (s0 >= 2) ? X1[base + (size_t)(s0 - 2) * DM + c] : 0.f;
      h1[DM + c] = (s0 >= 1) ? X1[base + (size_t)(s0 - 1) * DM + c] : 0.f;
    }
  }
}

// ---------------------------------------------------------------------------
// In-place depthwise causal conv (KS=3); weight indexed d = c & 63.
// ---------------------------------------------------------------------------
__global__ __launch_bounds__(256) void dwconv_ip(
    float* __restrict__ X, const float* __restrict__ halo,
    const float* __restrict__ w, const float* __restrict__ bias,
    int apply_fm) {
  const int c = blockIdx.x * 256 + threadIdx.x;
  const int b = blockIdx.y;
  const int z = blockIdx.z;
  const int s0 = z * 128;
  const int d = c & 63;
  const float w0 = w[d * 3 + 0], w1 = w[d * 3 + 1], w2 = w[d * 3 + 2];
  const float bb = bias[d];
  const size_t base = (size_t)b * SS * DM + c;
  const float* hp = halo + (size_t)(b * 32 + z) * 2 * DM;

  float xm2 = hp[c];
  float xm1 = hp[DM + c];
  for (int s = s0; s < s0 + 128; ++s) {
    const float xc = X[base + (size_t)s * DM];
    float y = bb + w0 * xm2 + w1 * xm1 + w2 * xc;
    if (apply_fm) y = (y > 0.f) ? (y + 1.f) : expf(y);
    X[base + (size_t)s * DM] = y;
    xm2 = xm1;
    xm1 = xc;
  }
}

// ---------------------------------------------------------------------------
// Partial KV: KVp[bh][chunk][d][e], Ksp[bh][chunk][d]. Deterministic.
// ---------------------------------------------------------------------------
__global__ __launch_bounds__(256) void kv_accum(
    const float* __restrict__ Kp, const float* __restrict__ Vp,
    float* __restrict__ KVp, float* __restrict__ Ksp) {
  const int bh = blockIdx.x;
  const int b = bh >> 4, h = bh & 15;
  const int chunk = blockIdx.y;
  const int s0 = chunk * 512;
  const int t = threadIdx.x;
  __shared__ float Ks[32][64];
  __shared__ float Vs[32][64];

  float acc[16];
#pragma unroll
  for (int j = 0; j < 16; ++j) acc[j] = 0.f;
  float ks = 0.f;
  const int d = t & 63;
  const int eg = t >> 6;
  const int e0 = eg * 16;
  const size_t basek = ((size_t)b * SS + s0) * DM + h * HD;

  for (int c = 0; c < 512; c += 32) {
    __syncthreads();
#pragma unroll
    for (int p = 0; p < 2; ++p) {
      const int lin = t * 4 + p * 1024;
      const int sl = lin >> 6, dd = lin & 63;
      *(float4*)&Ks[sl][dd] = *(const float4*)&Kp[basek + (size_t)(c + sl) * DM + dd];
      *(float4*)&Vs[sl][dd] = *(const float4*)&Vp[basek + (size_t)(c + sl) * DM + dd];
    }
    __syncthreads();
#pragma unroll 4
    for (int ss = 0; ss < 32; ++ss) {
      const float kd = Ks[ss][d];
      if (eg == 0) ks += kd;
#pragma unroll
      for (int j = 0; j < 16; ++j)
        acc[j] = fmaf(kd, Vs[ss][e0 + j], acc[j]);
    }
  }
  float* kvp = &KVp[((size_t)bh * 8 + chunk) * 4096 + d * 64 + e0];
#pragma unroll
  for (int j = 0; j < 16; ++j) kvp[j] = acc[j];
  if (eg == 0) Ksp[(bh * 8 + chunk) * 64 + d] = ks;
}

__global__ __launch_bounds__(256) void kv_reduce(
    const float* __restrict__ KVp, const float* __restrict__ Ksp,
    float* __restrict__ KV, float* __restrict__ Ksum) {
  const int bh = blockIdx.x;
  const int t = threadIdx.x;
  for (int i = t; i < 4096; i += 256) {
    float s = 0.f;
#pragma unroll
    for (int c = 0; c < 8; ++c) s += KVp[((size_t)bh * 8 + c) * 4096 + i];
    KV[(size_t)bh * 4096 + i] = s;
  }
  if (t < 64) {
    float s = 0.f;
#pragma unroll
    for (int c = 0; c < 8; ++c) s += Ksp[(bh * 8 + c) * 64 + t];
    Ksum[bh * 64 + t] = s;
  }
}

// ---------------------------------------------------------------------------
// V_new = Z * (Q @ KV); writes (hi,lo) f16 planes directly (feeds out-GEMM).
// ---------------------------------------------------------------------------
__global__ __launch_bounds__(256) void attn_apply(
    const float* __restrict__ Qp, const float* __restrict__ KV,
    const float* __restrict__ Ksum, _Float16* __restrict__ Ohi,
    _Float16* __restrict__ Olo) {
  const int bh = blockIdx.x;
  const int b = bh >> 4, h = bh & 15;
  const int s0 = blockIdx.y * 64;
  const int t = threadIdx.x;
  __shared__ float Qs[64][68];
  __shared__ float KVs[64][68];
  __shared__ float kse[64];
  const size_t baseq = ((size_t)b * SS + s0) * DM + h * HD;

#pragma unroll
  for (int p = 0; p < 4; ++p) {
    const int lin = t * 4 + p * 1024;
    const int r = lin >> 6, dd = lin & 63;
    *(float4*)&Qs[r][dd] = *(const float4*)&Qp[baseq + (size_t)r * DM + dd];
    *(float4*)&KVs[r][dd] = *(const float4*)&KV[(size_t)bh * 4096 + lin];
  }
  if (t < 64) kse[t] = Ksum[bh * 64 + t] + 1e-6f;
  __syncthreads();

  const int r = t >> 2;
  const int e0 = (t & 3) * 16;
  float acc[16];
#pragma unroll
  for (int j = 0; j < 16; ++j) acc[j] = 0.f;
  float den = 0.f;
#pragma unroll 8
  for (int dd = 0; dd < 64; ++dd) {
    const float qv = Qs[r][dd];
    den = fmaf(qv, kse[dd], den);
#pragma unroll
    for (int j = 0; j < 16; ++j)
      acc[j] = fmaf(qv, KVs[dd][e0 + j], acc[j]);
  }
  const float z = 1.0f / den;
  const size_t idx = baseq + (size_t)r * DM + e0;
  half8 hv[2], lv[2];
#pragma unroll
  for (int g = 0; g < 2; ++g)
#pragma unroll
    for (int j = 0; j < 8; ++j) {
      const float v = acc[g * 8 + j] * z;
      const _Float16 hh = (_Float16)v;
      hv[g][j] = hh;
      lv[g][j] = (_Float16)(v - (float)hh);
    }
  *(half8*)&Ohi[idx] = hv[0];
  *(half8*)&Ohi[idx + 8] = hv[1];
  *(half8*)&Olo[idx] = lv[0];
  *(half8*)&Olo[idx + 8] = lv[1];
}

// ---------------------------------------------------------------------------
extern "C" void kernel_launch(void* const* d_in, const int* in_sizes, int n_in,
                              void* d_out, int out_size, void* d_ws, size_t ws_size,
                              hipStream_t stream) {
  const float* query = (const float*)d_in[0];
  const float* key   = (const float*)d_in[1];
  const float* value = (const float*)d_in[2];
  const float* q_w = (const float*)d_in[3];
  const float* q_b = (const float*)d_in[4];
  const float* k_w = (const float*)d_in[5];
  const float* k_b = (const float*)d_in[6];
  const float* v_w = (const float*)d_in[7];
  const float* v_b = (const float*)d_in[8];
  const float* o_w = (const float*)d_in[9];
  const float* o_b = (const float*)d_in[10];
  const float* qc_w = (const float*)d_in[11];
  const float* qc_b = (const float*)d_in[12];
  const float* kc_w = (const float*)d_in[13];
  const float* kc_b = (const float*)d_in[14];
  const float* vc_w = (const float*)d_in[15];
  const float* vc_b = (const float*)d_in[16];
  float* out = (float*)d_out;

  // Workspace layout (~212 MB)
  float* ws = (float*)d_ws;
  float* buf0 = ws;                         // 64 MB fp32
  float* buf1 = ws + TSZ;                   // 64 MB fp32
  _Float16* Xhi = (_Float16*)(ws + 2 * TSZ);  // 32 MB
  _Float16* Xlo = Xhi + TSZ;                  // 32 MB
  _Float16* Whi = Xlo + TSZ;                  // 2 MB
  _Float16* Wlo = Whi + (1 << 20);            // 2 MB
  float* KVp  = (float*)(Wlo + (1 << 20));    // 8 MB
  float* Ksp  = KVp + (size_t)64 * 8 * 4096;
  float* KV   = Ksp + 64 * 8 * 64;
  float* Ksum = KV + (size_t)64 * 4096;
  float* halo0 = Ksum + 64 * 64;
  float* halo1 = halo0 + (size_t)BB * 32 * 2 * DM;

  const dim3 gg(DM / 128, NTOK / 128);    // (8,128)
  const dim3 cg(DM / 256, BB, SS / 128);  // (4,4,32)
  const dim3 hg(SS / 128, BB);            // (32,4)
  const int nX4 = (int)(TSZ / 4);         // 4,194,304
  const int nW4 = DM * DM / 4;            // 262,144

  // K path
  split_f32<<<nW4 / 256, 256, 0, stream>>>(k_w, Whi, Wlo, nW4);
  split_f32<<<nX4 / 256, 256, 0, stream>>>(key, Xhi, Xlo, nX4);
  gemm_split_nt<<<gg, 256, 0, stream>>>(Xhi, Xlo, Whi, Wlo, k_b, buf0, NTOK, DM, DM);
  // V path
  split_f32<<<nW4 / 256, 256, 0, stream>>>(v_w, Whi, Wlo, nW4);
  split_f32<<<nX4 / 256, 256, 0, stream>>>(value, Xhi, Xlo, nX4);
  gemm_split_nt<<<gg, 256, 0, stream>>>(Xhi, Xlo, Whi, Wlo, v_b, buf1, NTOK, DM, DM);

  halo_save2<<<hg, 256, 0, stream>>>(buf0, halo0, buf1, halo1);
  dwconv_ip<<<cg, 256, 0, stream>>>(buf0, halo0, kc_w, kc_b, 1);  // K (fm)
  dwconv_ip<<<cg, 256, 0, stream>>>(buf1, halo1, vc_w, vc_b, 0);  // V
  kv_accum<<<dim3(64, 8), 256, 0, stream>>>(buf0, buf1, KVp, Ksp);
  kv_reduce<<<64, 256, 0, stream>>>(KVp, Ksp, KV, Ksum);

  // Q path
  split_f32<<<nW4 / 256, 256, 0, stream>>>(q_w, Whi, Wlo, nW4);
  split_f32<<<nX4 / 256, 256, 0, stream>>>(query, Xhi, Xlo, nX4);
  gemm_split_nt<<<gg, 256, 0, stream>>>(Xhi, Xlo, Whi, Wlo, q_b, buf0, NTOK, DM, DM);
  halo_save2<<<hg, 256, 0, stream>>>(buf0, halo0, nullptr, nullptr);
  dwconv_ip<<<cg, 256, 0, stream>>>(buf0, halo0, qc_w, qc_b, 1);  // Q (fm)
  attn_apply<<<dim3(64, 64), 256, 0, stream>>>(buf0, KV, Ksum, Xhi, Xlo);

  // Output projection
  split_f32<<<nW4 / 256, 256, 0, stream>>>(o_w, Whi, Wlo, nW4);
  gemm_split_nt<<<gg, 256, 0, stream>>>(Xhi, Xlo, Whi, Wlo, o_b, out, NTOK, DM, DM);
}

// Round 4
// 879.165 us; speedup vs baseline: 2.3658x; 1.0706x over previous
//
#include <hip/hip_runtime.h>
#include <hip/hip_bf16.h>
#include <math.h>

// Problem constants
#define BB 4
#define SS 4096
#define DM 1024
#define HH 16
#define HD 64
#define NTOK (BB * SS)          // 16384 rows
#define TSZ ((size_t)NTOK * DM) // 16777216 elements per activation plane

typedef _Float16 half8 __attribute__((ext_vector_type(8)));
typedef _Float16 half4v __attribute__((ext_vector_type(4)));
typedef float floatx4 __attribute__((ext_vector_type(4)));

__device__ __forceinline__ void gload16(const void* g, void* l) {
  __builtin_amdgcn_global_load_lds(
      (const __attribute__((address_space(1))) void*)g,
      (__attribute__((address_space(3))) void*)l, 16, 0, 0);
}

// ---------------------------------------------------------------------------
// Split fp32 -> (hi, lo) f16 planes.  x = hi + lo + O(2^-22 |x|).
// ---------------------------------------------------------------------------
__global__ __launch_bounds__(256) void split_f32(
    const float* __restrict__ X, _Float16* __restrict__ hi,
    _Float16* __restrict__ lo, int n4) {
  const int i = blockIdx.x * 256 + threadIdx.x;
  if (i >= n4) return;
  const float4 x = ((const float4*)X)[i];
  half4v h, l;
  h.x = (_Float16)x.x; l.x = (_Float16)(x.x - (float)h.x);
  h.y = (_Float16)x.y; l.y = (_Float16)(x.y - (float)h.y);
  h.z = (_Float16)x.z; l.z = (_Float16)(x.z - (float)h.z);
  h.w = (_Float16)x.w; l.w = (_Float16)(x.w - (float)h.w);
  ((half4v*)hi)[i] = h;
  ((half4v*)lo)[i] = l;
}

// All 4 weight matrices split in one dispatch. Arena: hi/lo each 4*(1<<20) f16.
__global__ __launch_bounds__(256) void split_w4(
    const float* __restrict__ w0, const float* __restrict__ w1,
    const float* __restrict__ w2, const float* __restrict__ w3,
    _Float16* __restrict__ hi, _Float16* __restrict__ lo) {
  const int wi = blockIdx.y;
  const float* src = (wi == 0) ? w0 : (wi == 1) ? w1 : (wi == 2) ? w2 : w3;
  const int i = blockIdx.x * 256 + threadIdx.x;          // < 262144
  const size_t off = ((size_t)wi << 20) >> 2;            // in float4 units
  const float4 x = ((const float4*)src)[i];
  half4v h, l;
  h.x = (_Float16)x.x; l.x = (_Float16)(x.x - (float)h.x);
  h.y = (_Float16)x.y; l.y = (_Float16)(x.y - (float)h.y);
  h.z = (_Float16)x.z; l.z = (_Float16)(x.z - (float)h.z);
  h.w = (_Float16)x.w; l.w = (_Float16)(x.w - (float)h.w);
  ((half4v*)hi)[off + i] = h;
  ((half4v*)lo)[off + i] = l;
}

// ---------------------------------------------------------------------------
// Split-precision MFMA GEMM:  C[M,N] = A[M,K] @ W[N,K]^T + bias
// (unchanged from round 3: 128x128 tile, BK=32, global_load_lds 16B, 3-MFMA
// split product, ~855 TF raw)
// ---------------------------------------------------------------------------
__global__ __launch_bounds__(256) void gemm_split_nt(
    const _Float16* __restrict__ Ahi, const _Float16* __restrict__ Alo,
    const _Float16* __restrict__ Whi, const _Float16* __restrict__ Wlo,
    const float* __restrict__ bias, float* __restrict__ C,
    int M, int N, int K) {
  __shared__ _Float16 sAh[128 * 32];
  __shared__ _Float16 sAl[128 * 32];
  __shared__ _Float16 sBh[128 * 32];
  __shared__ _Float16 sBl[128 * 32];

  const int t = threadIdx.x;
  const int w = t >> 6, lane = t & 63;
  const int bm = blockIdx.y * 128, bn = blockIdx.x * 128;
  const int mbase = (w & 1) * 64, nbase = (w >> 1) * 64;
  const int fm = lane & 15;
  const int fk = (lane >> 4) * 8;

  floatx4 acc[4][4];
#pragma unroll
  for (int i = 0; i < 4; ++i)
#pragma unroll
    for (int j = 0; j < 4; ++j) acc[i][j] = (floatx4){0.f, 0.f, 0.f, 0.f};

  const int r0 = t >> 2, g0 = (t & 3) * 8;
  const int r1 = (t + 256) >> 2, g1 = (t & 3) * 8;
  const int lo0 = (w * 64) * 8;
  const int lo1 = (256 + w * 64) * 8;

  const _Float16* pAh0 = Ahi + (size_t)(bm + r0) * K + g0;
  const _Float16* pAh1 = Ahi + (size_t)(bm + r1) * K + g1;
  const _Float16* pAl0 = Alo + (size_t)(bm + r0) * K + g0;
  const _Float16* pAl1 = Alo + (size_t)(bm + r1) * K + g1;
  const _Float16* pBh0 = Whi + (size_t)(bn + r0) * K + g0;
  const _Float16* pBh1 = Whi + (size_t)(bn + r1) * K + g1;
  const _Float16* pBl0 = Wlo + (size_t)(bn + r0) * K + g0;
  const _Float16* pBl1 = Wlo + (size_t)(bn + r1) * K + g1;

  for (int k0 = 0; k0 < K; k0 += 32) {
    __syncthreads();
    gload16(pAh0 + k0, &sAh[lo0]);
    gload16(pAh1 + k0, &sAh[lo1]);
    gload16(pAl0 + k0, &sAl[lo0]);
    gload16(pAl1 + k0, &sAl[lo1]);
    gload16(pBh0 + k0, &sBh[lo0]);
    gload16(pBh1 + k0, &sBh[lo1]);
    gload16(pBl0 + k0, &sBl[lo0]);
    gload16(pBl1 + k0, &sBl[lo1]);
    __syncthreads();

    half8 ah[4], al[4], bh[4], bl[4];
#pragma unroll
    for (int i = 0; i < 4; ++i) {
      ah[i] = *(const half8*)&sAh[(mbase + i * 16 + fm) * 32 + fk];
      al[i] = *(const half8*)&sAl[(mbase + i * 16 + fm) * 32 + fk];
      bh[i] = *(const half8*)&sBh[(nbase + i * 16 + fm) * 32 + fk];
      bl[i] = *(const half8*)&sBl[(nbase + i * 16 + fm) * 32 + fk];
    }
#pragma unroll
    for (int i = 0; i < 4; ++i)
#pragma unroll
      for (int j = 0; j < 4; ++j) {
        acc[i][j] = __builtin_amdgcn_mfma_f32_16x16x32_f16(ah[i], bh[j], acc[i][j], 0, 0, 0);
        acc[i][j] = __builtin_amdgcn_mfma_f32_16x16x32_f16(ah[i], bl[j], acc[i][j], 0, 0, 0);
        acc[i][j] = __builtin_amdgcn_mfma_f32_16x16x32_f16(al[i], bh[j], acc[i][j], 0, 0, 0);
      }
  }

  const int cr = (lane >> 4) * 4;
#pragma unroll
  for (int i = 0; i < 4; ++i) {
    const int grow = bm + mbase + i * 16 + cr;
#pragma unroll
    for (int j = 0; j < 4; ++j) {
      const int gcol = bn + nbase + j * 16 + fm;
      const float bo = bias[gcol];
#pragma unroll
      for (int r = 0; r < 4; ++r)
        C[(size_t)(grow + r) * N + gcol] = acc[i][j][r] + bo;
    }
  }
}

// ---------------------------------------------------------------------------
// Fused conv(K)+fm, conv(V), and partial-KV accumulation. Reads RAW K,V
// projection outputs; conv applied in LDS with a 2-row causal halo.
// KVp[bh][chunk][d][e], Ksp[bh][chunk][d] partials (deterministic).
// ---------------------------------------------------------------------------
__global__ __launch_bounds__(256) void kv_accum_conv(
    const float* __restrict__ Kg, const float* __restrict__ Vg,
    const float* __restrict__ kc_w, const float* __restrict__ kc_b,
    const float* __restrict__ vc_w, const float* __restrict__ vc_b,
    float* __restrict__ KVp, float* __restrict__ Ksp) {
  const int bh = blockIdx.x;
  const int b = bh >> 4, h = bh & 15;
  const int chunk = blockIdx.y;
  const int s0 = chunk * 512;
  const int t = threadIdx.x;
  __shared__ float Kr[34][64], Vr[34][64];   // raw rows s-2..s+31
  __shared__ float Kc[32][64], Vc[32][64];   // conv'd rows
  __shared__ float kw0[64], kw1[64], kw2[64], kb_[64];
  __shared__ float vw0[64], vw1[64], vw2[64], vb_[64];

  if (t < 64) {
    kw0[t] = kc_w[t * 3 + 0]; kw1[t] = kc_w[t * 3 + 1]; kw2[t] = kc_w[t * 3 + 2];
    vw0[t] = vc_w[t * 3 + 0]; vw1[t] = vc_w[t * 3 + 1]; vw2[t] = vc_w[t * 3 + 2];
    kb_[t] = kc_b[t]; vb_[t] = vc_b[t];
  }

  float acc[16];
#pragma unroll
  for (int j = 0; j < 16; ++j) acc[j] = 0.f;
  float ks = 0.f;
  const int d = t & 63;
  const int eg = t >> 6;
  const int e0 = eg * 16;
  const size_t gbase = (size_t)b * SS * DM + h * HD;

  for (int c = 0; c < 512; c += 32) {
    __syncthreads();
    // stage 34 raw rows (s0+c-2 .. s0+c+31) of K and V
    for (int idx = t; idx < 544; idx += 256) {
      const int row = idx >> 4, col = (idx & 15) * 4;
      const int s = s0 + c - 2 + row;
      float4 k4 = make_float4(0.f, 0.f, 0.f, 0.f);
      float4 v4 = make_float4(0.f, 0.f, 0.f, 0.f);
      if (s >= 0) {
        k4 = *(const float4*)&Kg[gbase + (size_t)s * DM + col];
        v4 = *(const float4*)&Vg[gbase + (size_t)s * DM + col];
      }
      *(float4*)&Kr[row][col] = k4;
      *(float4*)&Vr[row][col] = v4;
    }
    __syncthreads();
    // conv + feature map into Kc/Vc
    for (int idx = t; idx < 2048; idx += 256) {
      const int row = idx >> 6, dd = idx & 63;
      float yk = kb_[dd] + kw0[dd] * Kr[row][dd] + kw1[dd] * Kr[row + 1][dd] +
                 kw2[dd] * Kr[row + 2][dd];
      Kc[row][dd] = (yk > 0.f) ? (yk + 1.f) : expf(yk);
      Vc[row][dd] = vb_[dd] + vw0[dd] * Vr[row][dd] + vw1[dd] * Vr[row + 1][dd] +
                    vw2[dd] * Vr[row + 2][dd];
    }
    __syncthreads();
#pragma unroll 4
    for (int ss = 0; ss < 32; ++ss) {
      const float kd = Kc[ss][d];
      if (eg == 0) ks += kd;
#pragma unroll
      for (int j = 0; j < 16; ++j)
        acc[j] = fmaf(kd, Vc[ss][e0 + j], acc[j]);
    }
  }
  float* kvp = &KVp[((size_t)bh * 8 + chunk) * 4096 + d * 64 + e0];
#pragma unroll
  for (int j = 0; j < 16; ++j) kvp[j] = acc[j];
  if (eg == 0) Ksp[(bh * 8 + chunk) * 64 + d] = ks;
}

__global__ __launch_bounds__(256) void kv_reduce(
    const float* __restrict__ KVp, const float* __restrict__ Ksp,
    float* __restrict__ KV, float* __restrict__ Ksum) {
  const int bh = blockIdx.x;
  const int t = threadIdx.x;
  for (int i = t; i < 4096; i += 256) {
    float s = 0.f;
#pragma unroll
    for (int c = 0; c < 8; ++c) s += KVp[((size_t)bh * 8 + c) * 4096 + i];
    KV[(size_t)bh * 4096 + i] = s;
  }
  if (t < 64) {
    float s = 0.f;
#pragma unroll
    for (int c = 0; c < 8; ++c) s += Ksp[(bh * 8 + c) * 64 + t];
    Ksum[bh * 64 + t] = s;
  }
}

// ---------------------------------------------------------------------------
// Fused conv(Q)+fm + attention apply. Reads RAW Q projection; conv in LDS
// with causal halo. Writes (hi,lo) f16 planes (feeds the output GEMM).
// ---------------------------------------------------------------------------
__global__ __launch_bounds__(256) void attn_apply_conv(
    const float* __restrict__ Qg, const float* __restrict__ KV,
    const float* __restrict__ Ksum, const float* __restrict__ qc_w,
    const float* __restrict__ qc_b, _Float16* __restrict__ Ohi,
    _Float16* __restrict__ Olo) {
  const int bh = blockIdx.x;
  const int b = bh >> 4, h = bh & 15;
  const int s0 = blockIdx.y * 64;
  const int t = threadIdx.x;
  __shared__ float Qr[66][68];   // raw rows s0-2..s0+63
  __shared__ float Qs[64][68];   // conv'd+fm
  __shared__ float KVs[64][68];
  __shared__ float kse[64];
  __shared__ float qw0[64], qw1[64], qw2[64], qb_[64];
  const size_t gbase = (size_t)b * SS * DM + h * HD;

  for (int idx = t; idx < 1056; idx += 256) {  // 66 rows * 16 float4
    const int row = idx >> 4, col = (idx & 15) * 4;
    const int s = s0 - 2 + row;
    float4 q4 = make_float4(0.f, 0.f, 0.f, 0.f);
    if (s >= 0) q4 = *(const float4*)&Qg[gbase + (size_t)s * DM + col];
    *(float4*)&Qr[row][col] = q4;
  }
  for (int idx = t; idx < 1024; idx += 256) {  // 64 rows * 16 float4
    const int row = idx >> 4, col = (idx & 15) * 4;
    *(float4*)&KVs[row][col] = *(const float4*)&KV[(size_t)bh * 4096 + row * 64 + col];
  }
  if (t < 64) {
    kse[t] = Ksum[bh * 64 + t] + 1e-6f;
    qw0[t] = qc_w[t * 3 + 0]; qw1[t] = qc_w[t * 3 + 1]; qw2[t] = qc_w[t * 3 + 2];
    qb_[t] = qc_b[t];
  }
  __syncthreads();
  for (int idx = t; idx < 4096; idx += 256) {
    const int row = idx >> 6, dd = idx & 63;
    float y = qb_[dd] + qw0[dd] * Qr[row][dd] + qw1[dd] * Qr[row + 1][dd] +
              qw2[dd] * Qr[row + 2][dd];
    Qs[row][dd] = (y > 0.f) ? (y + 1.f) : expf(y);
  }
  __syncthreads();

  const int r = t >> 2;
  const int e0 = (t & 3) * 16;
  float acc[16];
#pragma unroll
  for (int j = 0; j < 16; ++j) acc[j] = 0.f;
  float den = 0.f;
#pragma unroll 8
  for (int dd = 0; dd < 64; ++dd) {
    const float qv = Qs[r][dd];
    den = fmaf(qv, kse[dd], den);
#pragma unroll
    for (int j = 0; j < 16; ++j)
      acc[j] = fmaf(qv, KVs[dd][e0 + j], acc[j]);
  }
  const float z = 1.0f / den;
  const size_t idx = gbase + (size_t)(s0 + r) * DM + e0;
  half8 hv[2], lv[2];
#pragma unroll
  for (int g = 0; g < 2; ++g)
#pragma unroll
    for (int j = 0; j < 8; ++j) {
      const float v = acc[g * 8 + j] * z;
      const _Float16 hh = (_Float16)v;
      hv[g][j] = hh;
      lv[g][j] = (_Float16)(v - (float)hh);
    }
  *(half8*)&Ohi[idx] = hv[0];
  *(half8*)&Ohi[idx + 8] = hv[1];
  *(half8*)&Olo[idx] = lv[0];
  *(half8*)&Olo[idx + 8] = lv[1];
}

// ---------------------------------------------------------------------------
extern "C" void kernel_launch(void* const* d_in, const int* in_sizes, int n_in,
                              void* d_out, int out_size, void* d_ws, size_t ws_size,
                              hipStream_t stream) {
  const float* query = (const float*)d_in[0];
  const float* key   = (const float*)d_in[1];
  const float* value = (const float*)d_in[2];
  const float* q_w = (const float*)d_in[3];
  const float* q_b = (const float*)d_in[4];
  const float* k_w = (const float*)d_in[5];
  const float* k_b = (const float*)d_in[6];
  const float* v_w = (const float*)d_in[7];
  const float* v_b = (const float*)d_in[8];
  const float* o_w = (const float*)d_in[9];
  const float* o_b = (const float*)d_in[10];
  const float* qc_w = (const float*)d_in[11];
  const float* qc_b = (const float*)d_in[12];
  const float* kc_w = (const float*)d_in[13];
  const float* kc_b = (const float*)d_in[14];
  const float* vc_w = (const float*)d_in[15];
  const float* vc_b = (const float*)d_in[16];
  float* out = (float*)d_out;

  // Workspace layout (~227 MB)
  float* ws = (float*)d_ws;
  float* buf0 = ws;                           // raw K proj -> raw Q proj
  float* buf1 = ws + TSZ;                     // raw V proj
  _Float16* Xhi = (_Float16*)(ws + 2 * TSZ);  // 32 MB
  _Float16* Xlo = Xhi + TSZ;                  // 32 MB
  _Float16* Whi = Xlo + TSZ;                  // 4 x 2 MB arena
  _Float16* Wlo = Whi + 4 * (1 << 20);        // 4 x 2 MB arena
  float* KVp  = (float*)(Wlo + 4 * (1 << 20));
  float* Ksp  = KVp + (size_t)64 * 8 * 4096;
  float* KV   = Ksp + 64 * 8 * 64;
  float* Ksum = KV + (size_t)64 * 4096;

  // Weight arena order: 0=k_w 1=v_w 2=q_w 3=o_w
  _Float16* WhiK = Whi + 0 * (1 << 20); _Float16* WloK = Wlo + 0 * (1 << 20);
  _Float16* WhiV = Whi + 1 * (1 << 20); _Float16* WloV = Wlo + 1 * (1 << 20);
  _Float16* WhiQ = Whi + 2 * (1 << 20); _Float16* WloQ = Wlo + 2 * (1 << 20);
  _Float16* WhiO = Whi + 3 * (1 << 20); _Float16* WloO = Wlo + 3 * (1 << 20);

  const dim3 gg(DM / 128, NTOK / 128);    // (8,128)
  const int nX4 = (int)(TSZ / 4);
  const int nW4 = DM * DM / 4;

  split_w4<<<dim3(nW4 / 256, 4), 256, 0, stream>>>(k_w, v_w, q_w, o_w, Whi, Wlo);

  // K path
  split_f32<<<nX4 / 256, 256, 0, stream>>>(key, Xhi, Xlo, nX4);
  gemm_split_nt<<<gg, 256, 0, stream>>>(Xhi, Xlo, WhiK, WloK, k_b, buf0, NTOK, DM, DM);
  // V path
  split_f32<<<nX4 / 256, 256, 0, stream>>>(value, Xhi, Xlo, nX4);
  gemm_split_nt<<<gg, 256, 0, stream>>>(Xhi, Xlo, WhiV, WloV, v_b, buf1, NTOK, DM, DM);

  // conv(K)+fm, conv(V) fused into KV accumulation
  kv_accum_conv<<<dim3(64, 8), 256, 0, stream>>>(buf0, buf1, kc_w, kc_b, vc_w,
                                                 vc_b, KVp, Ksp);
  kv_reduce<<<64, 256, 0, stream>>>(KVp, Ksp, KV, Ksum);

  // Q path
  split_f32<<<nX4 / 256, 256, 0, stream>>>(query, Xhi, Xlo, nX4);
  gemm_split_nt<<<gg, 256, 0, stream>>>(Xhi, Xlo, WhiQ, WloQ, q_b, buf0, NTOK, DM, DM);
  attn_apply_conv<<<dim3(64, 64), 256, 0, stream>>>(buf0, KV, Ksum, qc_w, qc_b,
                                                    Xhi, Xlo);

  // Output projection
  gemm_split_nt<<<gg, 256, 0, stream>>>(Xhi, Xlo, WhiO, WloO, o_b, out, NTOK, DM, DM);
}

// Round 5
// 834.189 us; speedup vs baseline: 2.4933x; 1.0539x over previous
//
#include <hip/hip_runtime.h>
#include <hip/hip_bf16.h>
#include <math.h>

// Problem constants
#define BB 4
#define SS 4096
#define DM 1024
#define HH 16
#define HD 64
#define NTOK (BB * SS)          // 16384 rows
#define TSZ ((size_t)NTOK * DM) // 16777216 elements per activation plane

typedef _Float16 half8 __attribute__((ext_vector_type(8)));
typedef _Float16 half4v __attribute__((ext_vector_type(4)));
typedef float floatx4 __attribute__((ext_vector_type(4)));

__device__ __forceinline__ void gload16(const void* g, void* l) {
  __builtin_amdgcn_global_load_lds(
      (const __attribute__((address_space(1))) void*)g,
      (__attribute__((address_space(3))) void*)l, 16, 0, 0);
}

// ---------------------------------------------------------------------------
// All 4 weight matrices split into (hi,lo) f16 planes in one dispatch.
// Arena: hi/lo each 4*(1<<20) f16. Order: 0=k_w 1=v_w 2=q_w 3=o_w.
// ---------------------------------------------------------------------------
__global__ __launch_bounds__(256) void split_w4(
    const float* __restrict__ w0, const float* __restrict__ w1,
    const float* __restrict__ w2, const float* __restrict__ w3,
    _Float16* __restrict__ hi, _Float16* __restrict__ lo) {
  const int wi = blockIdx.y;
  const float* src = (wi == 0) ? w0 : (wi == 1) ? w1 : (wi == 2) ? w2 : w3;
  const int i = blockIdx.x * 256 + threadIdx.x;          // < 262144
  const size_t off = ((size_t)wi << 20) >> 2;            // in float4 units
  const float4 x = ((const float4*)src)[i];
  half4v h, l;
  h.x = (_Float16)x.x; l.x = (_Float16)(x.x - (float)h.x);
  h.y = (_Float16)x.y; l.y = (_Float16)(x.y - (float)h.y);
  h.z = (_Float16)x.z; l.z = (_Float16)(x.z - (float)h.z);
  h.w = (_Float16)x.w; l.w = (_Float16)(x.w - (float)h.w);
  ((half4v*)hi)[off + i] = h;
  ((half4v*)lo)[off + i] = l;
}

// ---------------------------------------------------------------------------
// Batched QKV projection GEMM with ON-THE-FLY hi/lo split of raw fp32 A.
// z in {0,1,2} selects (key,value,query) -> (bufK, bufV, bufQ).
// A staged via global_load_dwordx4 -> cvt -> ds_write_b64 (split in VGPRs);
// W staged via global_load_lds from pre-split f16 planes.
// ---------------------------------------------------------------------------
__global__ __launch_bounds__(256) void qkv_gemm_rawA(
    const float* __restrict__ Ak, const float* __restrict__ Av,
    const float* __restrict__ Aq, const _Float16* __restrict__ WhiA,
    const _Float16* __restrict__ WloA, const float* __restrict__ bk,
    const float* __restrict__ bv, const float* __restrict__ bq,
    float* __restrict__ Ck, float* __restrict__ Cv, float* __restrict__ Cq) {
  __shared__ _Float16 sAh[128 * 32];
  __shared__ _Float16 sAl[128 * 32];
  __shared__ _Float16 sBh[128 * 32];
  __shared__ _Float16 sBl[128 * 32];

  const int z = blockIdx.z;
  const float* A = (z == 0) ? Ak : (z == 1) ? Av : Aq;
  const float* bias = (z == 0) ? bk : (z == 1) ? bv : bq;
  float* C = (z == 0) ? Ck : (z == 1) ? Cv : Cq;
  const _Float16* Whi = WhiA + ((size_t)z << 20);
  const _Float16* Wlo = WloA + ((size_t)z << 20);
  const int K = DM, N = DM;

  const int t = threadIdx.x;
  const int w = t >> 6, lane = t & 63;
  const int bm = blockIdx.y * 128, bn = blockIdx.x * 128;
  const int mbase = (w & 1) * 64, nbase = (w >> 1) * 64;
  const int fm = lane & 15;
  const int fk = (lane >> 4) * 8;

  floatx4 acc[4][4];
#pragma unroll
  for (int i = 0; i < 4; ++i)
#pragma unroll
    for (int j = 0; j < 4; ++j) acc[i][j] = (floatx4){0.f, 0.f, 0.f, 0.f};

  // A staging: 128 rows x 32 K fp32 = 1024 float4 chunks; 4 per thread.
  const int ar = t >> 3;          // base row 0..31
  const int ac = (t & 7) * 4;     // k-col 0,4,...,28
  const float* pA[4];
#pragma unroll
  for (int p = 0; p < 4; ++p)
    pA[p] = A + (size_t)(bm + ar + 32 * p) * K + ac;

  // W staging (16B chunks): thread t covers chunks t and t+256.
  const int r0 = t >> 2, g0 = (t & 3) * 8;
  const int r1 = 64 + (t >> 2);
  const int lo0 = (w * 64) * 8;
  const int lo1 = (256 + w * 64) * 8;
  const _Float16* pBh0 = Whi + (size_t)(bn + r0) * K + g0;
  const _Float16* pBh1 = Whi + (size_t)(bn + r1) * K + g0;
  const _Float16* pBl0 = Wlo + (size_t)(bn + r0) * K + g0;
  const _Float16* pBl1 = Wlo + (size_t)(bn + r1) * K + g0;

  for (int k0 = 0; k0 < K; k0 += 32) {
    float4 av[4];
#pragma unroll
    for (int p = 0; p < 4; ++p) av[p] = *(const float4*)(pA[p] + k0);
    __syncthreads();
    gload16(pBh0 + k0, &sBh[lo0]);
    gload16(pBh1 + k0, &sBh[lo1]);
    gload16(pBl0 + k0, &sBl[lo0]);
    gload16(pBl1 + k0, &sBl[lo1]);
#pragma unroll
    for (int p = 0; p < 4; ++p) {
      half4v h, l;
      h.x = (_Float16)av[p].x; l.x = (_Float16)(av[p].x - (float)h.x);
      h.y = (_Float16)av[p].y; l.y = (_Float16)(av[p].y - (float)h.y);
      h.z = (_Float16)av[p].z; l.z = (_Float16)(av[p].z - (float)h.z);
      h.w = (_Float16)av[p].w; l.w = (_Float16)(av[p].w - (float)h.w);
      const int off = (ar + 32 * p) * 32 + ac;
      *(half4v*)&sAh[off] = h;
      *(half4v*)&sAl[off] = l;
    }
    __syncthreads();

    half8 ah[4], al[4], bh[4], bl[4];
#pragma unroll
    for (int i = 0; i < 4; ++i) {
      ah[i] = *(const half8*)&sAh[(mbase + i * 16 + fm) * 32 + fk];
      al[i] = *(const half8*)&sAl[(mbase + i * 16 + fm) * 32 + fk];
      bh[i] = *(const half8*)&sBh[(nbase + i * 16 + fm) * 32 + fk];
      bl[i] = *(const half8*)&sBl[(nbase + i * 16 + fm) * 32 + fk];
    }
#pragma unroll
    for (int i = 0; i < 4; ++i)
#pragma unroll
      for (int j = 0; j < 4; ++j) {
        acc[i][j] = __builtin_amdgcn_mfma_f32_16x16x32_f16(ah[i], bh[j], acc[i][j], 0, 0, 0);
        acc[i][j] = __builtin_amdgcn_mfma_f32_16x16x32_f16(ah[i], bl[j], acc[i][j], 0, 0, 0);
        acc[i][j] = __builtin_amdgcn_mfma_f32_16x16x32_f16(al[i], bh[j], acc[i][j], 0, 0, 0);
      }
  }

  const int cr = (lane >> 4) * 4;
#pragma unroll
  for (int i = 0; i < 4; ++i) {
    const int grow = bm + mbase + i * 16 + cr;
#pragma unroll
    for (int j = 0; j < 4; ++j) {
      const int gcol = bn + nbase + j * 16 + fm;
      const float bo = bias[gcol];
#pragma unroll
      for (int r = 0; r < 4; ++r)
        C[(size_t)(grow + r) * N + gcol] = acc[i][j][r] + bo;
    }
  }
}

// ---------------------------------------------------------------------------
// Split-precision MFMA GEMM on pre-split (hi,lo) f16 planes (output proj).
// ---------------------------------------------------------------------------
__global__ __launch_bounds__(256) void gemm_split_nt(
    const _Float16* __restrict__ Ahi, const _Float16* __restrict__ Alo,
    const _Float16* __restrict__ Whi, const _Float16* __restrict__ Wlo,
    const float* __restrict__ bias, float* __restrict__ C,
    int M, int N, int K) {
  __shared__ _Float16 sAh[128 * 32];
  __shared__ _Float16 sAl[128 * 32];
  __shared__ _Float16 sBh[128 * 32];
  __shared__ _Float16 sBl[128 * 32];

  const int t = threadIdx.x;
  const int w = t >> 6, lane = t & 63;
  const int bm = blockIdx.y * 128, bn = blockIdx.x * 128;
  const int mbase = (w & 1) * 64, nbase = (w >> 1) * 64;
  const int fm = lane & 15;
  const int fk = (lane >> 4) * 8;

  floatx4 acc[4][4];
#pragma unroll
  for (int i = 0; i < 4; ++i)
#pragma unroll
    for (int j = 0; j < 4; ++j) acc[i][j] = (floatx4){0.f, 0.f, 0.f, 0.f};

  const int r0 = t >> 2, g0 = (t & 3) * 8;
  const int r1 = (t + 256) >> 2, g1 = (t & 3) * 8;
  const int lo0 = (w * 64) * 8;
  const int lo1 = (256 + w * 64) * 8;

  const _Float16* pAh0 = Ahi + (size_t)(bm + r0) * K + g0;
  const _Float16* pAh1 = Ahi + (size_t)(bm + r1) * K + g1;
  const _Float16* pAl0 = Alo + (size_t)(bm + r0) * K + g0;
  const _Float16* pAl1 = Alo + (size_t)(bm + r1) * K + g1;
  const _Float16* pBh0 = Whi + (size_t)(bn + r0) * K + g0;
  const _Float16* pBh1 = Whi + (size_t)(bn + r1) * K + g1;
  const _Float16* pBl0 = Wlo + (size_t)(bn + r0) * K + g0;
  const _Float16* pBl1 = Wlo + (size_t)(bn + r1) * K + g1;

  for (int k0 = 0; k0 < K; k0 += 32) {
    __syncthreads();
    gload16(pAh0 + k0, &sAh[lo0]);
    gload16(pAh1 + k0, &sAh[lo1]);
    gload16(pAl0 + k0, &sAl[lo0]);
    gload16(pAl1 + k0, &sAl[lo1]);
    gload16(pBh0 + k0, &sBh[lo0]);
    gload16(pBh1 + k0, &sBh[lo1]);
    gload16(pBl0 + k0, &sBl[lo0]);
    gload16(pBl1 + k0, &sBl[lo1]);
    __syncthreads();

    half8 ah[4], al[4], bh[4], bl[4];
#pragma unroll
    for (int i = 0; i < 4; ++i) {
      ah[i] = *(const half8*)&sAh[(mbase + i * 16 + fm) * 32 + fk];
      al[i] = *(const half8*)&sAl[(mbase + i * 16 + fm) * 32 + fk];
      bh[i] = *(const half8*)&sBh[(nbase + i * 16 + fm) * 32 + fk];
      bl[i] = *(const half8*)&sBl[(nbase + i * 16 + fm) * 32 + fk];
    }
#pragma unroll
    for (int i = 0; i < 4; ++i)
#pragma unroll
      for (int j = 0; j < 4; ++j) {
        acc[i][j] = __builtin_amdgcn_mfma_f32_16x16x32_f16(ah[i], bh[j], acc[i][j], 0, 0, 0);
        acc[i][j] = __builtin_amdgcn_mfma_f32_16x16x32_f16(ah[i], bl[j], acc[i][j], 0, 0, 0);
        acc[i][j] = __builtin_amdgcn_mfma_f32_16x16x32_f16(al[i], bh[j], acc[i][j], 0, 0, 0);
      }
  }

  const int cr = (lane >> 4) * 4;
#pragma unroll
  for (int i = 0; i < 4; ++i) {
    const int grow = bm + mbase + i * 16 + cr;
#pragma unroll
    for (int j = 0; j < 4; ++j) {
      const int gcol = bn + nbase + j * 16 + fm;
      const float bo = bias[gcol];
#pragma unroll
      for (int r = 0; r < 4; ++r)
        C[(size_t)(grow + r) * N + gcol] = acc[i][j][r] + bo;
    }
  }
}

// ---------------------------------------------------------------------------
// Fused conv(K)+fm, conv(V), and partial-KV accumulation (raw K,V in).
// KVp[bh][chunk][d][e], Ksp[bh][chunk][d] partials (deterministic).
// ---------------------------------------------------------------------------
__global__ __launch_bounds__(256) void kv_accum_conv(
    const float* __restrict__ Kg, const float* __restrict__ Vg,
    const float* __restrict__ kc_w, const float* __restrict__ kc_b,
    const float* __restrict__ vc_w, const float* __restrict__ vc_b,
    float* __restrict__ KVp, float* __restrict__ Ksp) {
  const int bh = blockIdx.x;
  const int b = bh >> 4, h = bh & 15;
  const int chunk = blockIdx.y;
  const int s0 = chunk * 512;
  const int t = threadIdx.x;
  __shared__ float Kr[34][64], Vr[34][64];
  __shared__ float Kc[32][64], Vc[32][64];
  __shared__ float kw0[64], kw1[64], kw2[64], kb_[64];
  __shared__ float vw0[64], vw1[64], vw2[64], vb_[64];

  if (t < 64) {
    kw0[t] = kc_w[t * 3 + 0]; kw1[t] = kc_w[t * 3 + 1]; kw2[t] = kc_w[t * 3 + 2];
    vw0[t] = vc_w[t * 3 + 0]; vw1[t] = vc_w[t * 3 + 1]; vw2[t] = vc_w[t * 3 + 2];
    kb_[t] = kc_b[t]; vb_[t] = vc_b[t];
  }

  float acc[16];
#pragma unroll
  for (int j = 0; j < 16; ++j) acc[j] = 0.f;
  float ks = 0.f;
  const int d = t & 63;
  const int eg = t >> 6;
  const int e0 = eg * 16;
  const size_t gbase = (size_t)b * SS * DM + h * HD;

  for (int c = 0; c < 512; c += 32) {
    __syncthreads();
    for (int idx = t; idx < 544; idx += 256) {
      const int row = idx >> 4, col = (idx & 15) * 4;
      const int s = s0 + c - 2 + row;
      float4 k4 = make_float4(0.f, 0.f, 0.f, 0.f);
      float4 v4 = make_float4(0.f, 0.f, 0.f, 0.f);
      if (s >= 0) {
        k4 = *(const float4*)&Kg[gbase + (size_t)s * DM + col];
        v4 = *(const float4*)&Vg[gbase + (size_t)s * DM + col];
      }
      *(float4*)&Kr[row][col] = k4;
      *(float4*)&Vr[row][col] = v4;
    }
    __syncthreads();
    for (int idx = t; idx < 2048; idx += 256) {
      const int row = idx >> 6, dd = idx & 63;
      float yk = kb_[dd] + kw0[dd] * Kr[row][dd] + kw1[dd] * Kr[row + 1][dd] +
                 kw2[dd] * Kr[row + 2][dd];
      Kc[row][dd] = (yk > 0.f) ? (yk + 1.f) : expf(yk);
      Vc[row][dd] = vb_[dd] + vw0[dd] * Vr[row][dd] + vw1[dd] * Vr[row + 1][dd] +
                    vw2[dd] * Vr[row + 2][dd];
    }
    __syncthreads();
#pragma unroll 4
    for (int ss = 0; ss < 32; ++ss) {
      const float kd = Kc[ss][d];
      if (eg == 0) ks += kd;
#pragma unroll
      for (int j = 0; j < 16; ++j)
        acc[j] = fmaf(kd, Vc[ss][e0 + j], acc[j]);
    }
  }
  float* kvp = &KVp[((size_t)bh * 8 + chunk) * 4096 + d * 64 + e0];
#pragma unroll
  for (int j = 0; j < 16; ++j) kvp[j] = acc[j];
  if (eg == 0) Ksp[(bh * 8 + chunk) * 64 + d] = ks;
}

__global__ __launch_bounds__(256) void kv_reduce(
    const float* __restrict__ KVp, const float* __restrict__ Ksp,
    float* __restrict__ KV, float* __restrict__ Ksum) {
  const int bh = blockIdx.x;
  const int t = threadIdx.x;
  for (int i = t; i < 4096; i += 256) {
    float s = 0.f;
#pragma unroll
    for (int c = 0; c < 8; ++c) s += KVp[((size_t)bh * 8 + c) * 4096 + i];
    KV[(size_t)bh * 4096 + i] = s;
  }
  if (t < 64) {
    float s = 0.f;
#pragma unroll
    for (int c = 0; c < 8; ++c) s += Ksp[(bh * 8 + c) * 64 + t];
    Ksum[bh * 64 + t] = s;
  }
}

// ---------------------------------------------------------------------------
// Fused conv(Q)+fm + attention apply (raw Q in); writes (hi,lo) f16 planes.
// ---------------------------------------------------------------------------
__global__ __launch_bounds__(256) void attn_apply_conv(
    const float* __restrict__ Qg, const float* __restrict__ KV,
    const float* __restrict__ Ksum, const float* __restrict__ qc_w,
    const float* __restrict__ qc_b, _Float16* __restrict__ Ohi,
    _Float16* __restrict__ Olo) {
  const int bh = blockIdx.x;
  const int b = bh >> 4, h = bh & 15;
  const int s0 = blockIdx.y * 64;
  const int t = threadIdx.x;
  __shared__ float Qr[66][68];
  __shared__ float Qs[64][68];
  __shared__ float KVs[64][68];
  __shared__ float kse[64];
  __shared__ float qw0[64], qw1[64], qw2[64], qb_[64];
  const size_t gbase = (size_t)b * SS * DM + h * HD;

  for (int idx = t; idx < 1056; idx += 256) {
    const int row = idx >> 4, col = (idx & 15) * 4;
    const int s = s0 - 2 + row;
    float4 q4 = make_float4(0.f, 0.f, 0.f, 0.f);
    if (s >= 0) q4 = *(const float4*)&Qg[gbase + (size_t)s * DM + col];
    *(float4*)&Qr[row][col] = q4;
  }
  for (int idx = t; idx < 1024; idx += 256) {
    const int row = idx >> 4, col = (idx & 15) * 4;
    *(float4*)&KVs[row][col] = *(const float4*)&KV[(size_t)bh * 4096 + row * 64 + col];
  }
  if (t < 64) {
    kse[t] = Ksum[bh * 64 + t] + 1e-6f;
    qw0[t] = qc_w[t * 3 + 0]; qw1[t] = qc_w[t * 3 + 1]; qw2[t] = qc_w[t * 3 + 2];
    qb_[t] = qc_b[t];
  }
  __syncthreads();
  for (int idx = t; idx < 4096; idx += 256) {
    const int row = idx >> 6, dd = idx & 63;
    float y = qb_[dd] + qw0[dd] * Qr[row][dd] + qw1[dd] * Qr[row + 1][dd] +
              qw2[dd] * Qr[row + 2][dd];
    Qs[row][dd] = (y > 0.f) ? (y + 1.f) : expf(y);
  }
  __syncthreads();

  const int r = t >> 2;
  const int e0 = (t & 3) * 16;
  float acc[16];
#pragma unroll
  for (int j = 0; j < 16; ++j) acc[j] = 0.f;
  float den = 0.f;
#pragma unroll 8
  for (int dd = 0; dd < 64; ++dd) {
    const float qv = Qs[r][dd];
    den = fmaf(qv, kse[dd], den);
#pragma unroll
    for (int j = 0; j < 16; ++j)
      acc[j] = fmaf(qv, KVs[dd][e0 + j], acc[j]);
  }
  const float z = 1.0f / den;
  const size_t idx = gbase + (size_t)(s0 + r) * DM + e0;
  half8 hv[2], lv[2];
#pragma unroll
  for (int g = 0; g < 2; ++g)
#pragma unroll
    for (int j = 0; j < 8; ++j) {
      const float v = acc[g * 8 + j] * z;
      const _Float16 hh = (_Float16)v;
      hv[g][j] = hh;
      lv[g][j] = (_Float16)(v - (float)hh);
    }
  *(half8*)&Ohi[idx] = hv[0];
  *(half8*)&Ohi[idx + 8] = hv[1];
  *(half8*)&Olo[idx] = lv[0];
  *(half8*)&Olo[idx + 8] = lv[1];
}

// ---------------------------------------------------------------------------
extern "C" void kernel_launch(void* const* d_in, const int* in_sizes, int n_in,
                              void* d_out, int out_size, void* d_ws, size_t ws_size,
                              hipStream_t stream) {
  const float* query = (const float*)d_in[0];
  const float* key   = (const float*)d_in[1];
  const float* value = (const float*)d_in[2];
  const float* q_w = (const float*)d_in[3];
  const float* q_b = (const float*)d_in[4];
  const float* k_w = (const float*)d_in[5];
  const float* k_b = (const float*)d_in[6];
  const float* v_w = (const float*)d_in[7];
  const float* v_b = (const float*)d_in[8];
  const float* o_w = (const float*)d_in[9];
  const float* o_b = (const float*)d_in[10];
  const float* qc_w = (const float*)d_in[11];
  const float* qc_b = (const float*)d_in[12];
  const float* kc_w = (const float*)d_in[13];
  const float* kc_b = (const float*)d_in[14];
  const float* vc_w = (const float*)d_in[15];
  const float* vc_b = (const float*)d_in[16];
  float* out = (float*)d_out;

  // Workspace layout (~217 MB)
  float* ws = (float*)d_ws;
  float* buf0 = ws;                    // raw K proj; later attn-out hi plane
  float* buf1 = ws + TSZ;              // raw V proj; later attn-out lo plane
  float* buf2 = ws + 2 * TSZ;          // raw Q proj
  _Float16* Whi = (_Float16*)(ws + 3 * TSZ);  // 4 x 2 MB arena (k,v,q,o)
  _Float16* Wlo = Whi + 4 * (1 << 20);
  float* KVp  = (float*)(Wlo + 4 * (1 << 20));
  float* Ksp  = KVp + (size_t)64 * 8 * 4096;
  float* KV   = Ksp + 64 * 8 * 64;
  float* Ksum = KV + (size_t)64 * 4096;

  _Float16* WhiO = Whi + 3 * (1 << 20);
  _Float16* WloO = Wlo + 3 * (1 << 20);
  _Float16* Ohi = (_Float16*)buf0;
  _Float16* Olo = (_Float16*)buf1;

  const int nW4 = DM * DM / 4;

  // Weight arena order: 0=k_w 1=v_w 2=q_w 3=o_w
  split_w4<<<dim3(nW4 / 256, 4), 256, 0, stream>>>(k_w, v_w, q_w, o_w, Whi, Wlo);

  // Batched Q/K/V projections with in-kernel hi/lo split of raw inputs.
  qkv_gemm_rawA<<<dim3(DM / 128, NTOK / 128, 3), 256, 0, stream>>>(
      key, value, query, Whi, Wlo, k_b, v_b, q_b, buf0, buf1, buf2);

  // conv(K)+fm, conv(V) fused into KV accumulation
  kv_accum_conv<<<dim3(64, 8), 256, 0, stream>>>(buf0, buf1, kc_w, kc_b, vc_w,
                                                 vc_b, KVp, Ksp);
  kv_reduce<<<64, 256, 0, stream>>>(KVp, Ksp, KV, Ksum);

  // conv(Q)+fm + attention; writes hi/lo planes into buf0/buf1 (now dead)
  attn_apply_conv<<<dim3(64, 64), 256, 0, stream>>>(buf2, KV, Ksum, qc_w, qc_b,
                                                    Ohi, Olo);

  // Output projection
  gemm_split_nt<<<dim3(DM / 128, NTOK / 128), 256, 0, stream>>>(
      Ohi, Olo, WhiO, WloO, o_b, out, NTOK, DM, DM);
}

// Round 6
// 791.296 us; speedup vs baseline: 2.6285x; 1.0542x over previous
//
#include <hip/hip_runtime.h>
#include <hip/hip_bf16.h>
#include <math.h>

// Problem constants
#define BB 4
#define SS 4096
#define DM 1024
#define HH 16
#define HD 64
#define NTOK (BB * SS)          // 16384 rows
#define TSZ ((size_t)NTOK * DM) // 16777216 elements per activation plane

typedef _Float16 half8 __attribute__((ext_vector_type(8)));
typedef _Float16 half4v __attribute__((ext_vector_type(4)));
typedef float floatx4 __attribute__((ext_vector_type(4)));

__device__ __forceinline__ void gload16(const void* g, void* l) {
  __builtin_amdgcn_global_load_lds(
      (const __attribute__((address_space(1))) void*)g,
      (__attribute__((address_space(3))) void*)l, 16, 0, 0);
}

// ---------------------------------------------------------------------------
// All 4 weight matrices split into (hi,lo) f16 planes in one dispatch.
// Arena: hi/lo each 4*(1<<20) f16. Order: 0=k_w 1=v_w 2=q_w 3=o_w.
// ---------------------------------------------------------------------------
__global__ __launch_bounds__(256) void split_w4(
    const float* __restrict__ w0, const float* __restrict__ w1,
    const float* __restrict__ w2, const float* __restrict__ w3,
    _Float16* __restrict__ hi, _Float16* __restrict__ lo) {
  const int wi = blockIdx.y;
  const float* src = (wi == 0) ? w0 : (wi == 1) ? w1 : (wi == 2) ? w2 : w3;
  const int i = blockIdx.x * 256 + threadIdx.x;          // < 262144
  const size_t off = ((size_t)wi << 20) >> 2;            // in float4 units
  const float4 x = ((const float4*)src)[i];
  half4v h, l;
  h.x = (_Float16)x.x; l.x = (_Float16)(x.x - (float)h.x);
  h.y = (_Float16)x.y; l.y = (_Float16)(x.y - (float)h.y);
  h.z = (_Float16)x.z; l.z = (_Float16)(x.z - (float)h.z);
  h.w = (_Float16)x.w; l.w = (_Float16)(x.w - (float)h.w);
  ((half4v*)hi)[off + i] = h;
  ((half4v*)lo)[off + i] = l;
}

// ---------------------------------------------------------------------------
// Batched QKV projection GEMM with ON-THE-FLY hi/lo split of raw fp32 A.
// ---------------------------------------------------------------------------
__global__ __launch_bounds__(256) void qkv_gemm_rawA(
    const float* __restrict__ Ak, const float* __restrict__ Av,
    const float* __restrict__ Aq, const _Float16* __restrict__ WhiA,
    const _Float16* __restrict__ WloA, const float* __restrict__ bk,
    const float* __restrict__ bv, const float* __restrict__ bq,
    float* __restrict__ Ck, float* __restrict__ Cv, float* __restrict__ Cq) {
  __shared__ _Float16 sAh[128 * 32];
  __shared__ _Float16 sAl[128 * 32];
  __shared__ _Float16 sBh[128 * 32];
  __shared__ _Float16 sBl[128 * 32];

  const int z = blockIdx.z;
  const float* A = (z == 0) ? Ak : (z == 1) ? Av : Aq;
  const float* bias = (z == 0) ? bk : (z == 1) ? bv : bq;
  float* C = (z == 0) ? Ck : (z == 1) ? Cv : Cq;
  const _Float16* Whi = WhiA + ((size_t)z << 20);
  const _Float16* Wlo = WloA + ((size_t)z << 20);
  const int K = DM, N = DM;

  const int t = threadIdx.x;
  const int w = t >> 6, lane = t & 63;
  const int bm = blockIdx.y * 128, bn = blockIdx.x * 128;
  const int mbase = (w & 1) * 64, nbase = (w >> 1) * 64;
  const int fm = lane & 15;
  const int fk = (lane >> 4) * 8;

  floatx4 acc[4][4];
#pragma unroll
  for (int i = 0; i < 4; ++i)
#pragma unroll
    for (int j = 0; j < 4; ++j) acc[i][j] = (floatx4){0.f, 0.f, 0.f, 0.f};

  const int ar = t >> 3;
  const int ac = (t & 7) * 4;
  const float* pA[4];
#pragma unroll
  for (int p = 0; p < 4; ++p)
    pA[p] = A + (size_t)(bm + ar + 32 * p) * K + ac;

  const int r0 = t >> 2, g0 = (t & 3) * 8;
  const int r1 = 64 + (t >> 2);
  const int lo0 = (w * 64) * 8;
  const int lo1 = (256 + w * 64) * 8;
  const _Float16* pBh0 = Whi + (size_t)(bn + r0) * K + g0;
  const _Float16* pBh1 = Whi + (size_t)(bn + r1) * K + g0;
  const _Float16* pBl0 = Wlo + (size_t)(bn + r0) * K + g0;
  const _Float16* pBl1 = Wlo + (size_t)(bn + r1) * K + g0;

  for (int k0 = 0; k0 < K; k0 += 32) {
    float4 av[4];
#pragma unroll
    for (int p = 0; p < 4; ++p) av[p] = *(const float4*)(pA[p] + k0);
    __syncthreads();
    gload16(pBh0 + k0, &sBh[lo0]);
    gload16(pBh1 + k0, &sBh[lo1]);
    gload16(pBl0 + k0, &sBl[lo0]);
    gload16(pBl1 + k0, &sBl[lo1]);
#pragma unroll
    for (int p = 0; p < 4; ++p) {
      half4v h, l;
      h.x = (_Float16)av[p].x; l.x = (_Float16)(av[p].x - (float)h.x);
      h.y = (_Float16)av[p].y; l.y = (_Float16)(av[p].y - (float)h.y);
      h.z = (_Float16)av[p].z; l.z = (_Float16)(av[p].z - (float)h.z);
      h.w = (_Float16)av[p].w; l.w = (_Float16)(av[p].w - (float)h.w);
      const int off = (ar + 32 * p) * 32 + ac;
      *(half4v*)&sAh[off] = h;
      *(half4v*)&sAl[off] = l;
    }
    __syncthreads();

    half8 ah[4], al[4], bh[4], bl[4];
#pragma unroll
    for (int i = 0; i < 4; ++i) {
      ah[i] = *(const half8*)&sAh[(mbase + i * 16 + fm) * 32 + fk];
      al[i] = *(const half8*)&sAl[(mbase + i * 16 + fm) * 32 + fk];
      bh[i] = *(const half8*)&sBh[(nbase + i * 16 + fm) * 32 + fk];
      bl[i] = *(const half8*)&sBl[(nbase + i * 16 + fm) * 32 + fk];
    }
#pragma unroll
    for (int i = 0; i < 4; ++i)
#pragma unroll
      for (int j = 0; j < 4; ++j) {
        acc[i][j] = __builtin_amdgcn_mfma_f32_16x16x32_f16(ah[i], bh[j], acc[i][j], 0, 0, 0);
        acc[i][j] = __builtin_amdgcn_mfma_f32_16x16x32_f16(ah[i], bl[j], acc[i][j], 0, 0, 0);
        acc[i][j] = __builtin_amdgcn_mfma_f32_16x16x32_f16(al[i], bh[j], acc[i][j], 0, 0, 0);
      }
  }

  const int cr = (lane >> 4) * 4;
#pragma unroll
  for (int i = 0; i < 4; ++i) {
    const int grow = bm + mbase + i * 16 + cr;
#pragma unroll
    for (int j = 0; j < 4; ++j) {
      const int gcol = bn + nbase + j * 16 + fm;
      const float bo = bias[gcol];
#pragma unroll
      for (int r = 0; r < 4; ++r)
        C[(size_t)(grow + r) * N + gcol] = acc[i][j][r] + bo;
    }
  }
}

// ---------------------------------------------------------------------------
// Single-input rawA GEMM (output projection): C = A @ W^T + bias.
// ---------------------------------------------------------------------------
__global__ __launch_bounds__(256) void o_gemm_rawA(
    const float* __restrict__ A, const _Float16* __restrict__ Whi,
    const _Float16* __restrict__ Wlo, const float* __restrict__ bias,
    float* __restrict__ C) {
  __shared__ _Float16 sAh[128 * 32];
  __shared__ _Float16 sAl[128 * 32];
  __shared__ _Float16 sBh[128 * 32];
  __shared__ _Float16 sBl[128 * 32];

  const int K = DM, N = DM;
  const int t = threadIdx.x;
  const int w = t >> 6, lane = t & 63;
  const int bm = blockIdx.y * 128, bn = blockIdx.x * 128;
  const int mbase = (w & 1) * 64, nbase = (w >> 1) * 64;
  const int fm = lane & 15;
  const int fk = (lane >> 4) * 8;

  floatx4 acc[4][4];
#pragma unroll
  for (int i = 0; i < 4; ++i)
#pragma unroll
    for (int j = 0; j < 4; ++j) acc[i][j] = (floatx4){0.f, 0.f, 0.f, 0.f};

  const int ar = t >> 3;
  const int ac = (t & 7) * 4;
  const float* pA[4];
#pragma unroll
  for (int p = 0; p < 4; ++p)
    pA[p] = A + (size_t)(bm + ar + 32 * p) * K + ac;

  const int r0 = t >> 2, g0 = (t & 3) * 8;
  const int r1 = 64 + (t >> 2);
  const int lo0 = (w * 64) * 8;
  const int lo1 = (256 + w * 64) * 8;
  const _Float16* pBh0 = Whi + (size_t)(bn + r0) * K + g0;
  const _Float16* pBh1 = Whi + (size_t)(bn + r1) * K + g0;
  const _Float16* pBl0 = Wlo + (size_t)(bn + r0) * K + g0;
  const _Float16* pBl1 = Wlo + (size_t)(bn + r1) * K + g0;

  for (int k0 = 0; k0 < K; k0 += 32) {
    float4 av[4];
#pragma unroll
    for (int p = 0; p < 4; ++p) av[p] = *(const float4*)(pA[p] + k0);
    __syncthreads();
    gload16(pBh0 + k0, &sBh[lo0]);
    gload16(pBh1 + k0, &sBh[lo1]);
    gload16(pBl0 + k0, &sBl[lo0]);
    gload16(pBl1 + k0, &sBl[lo1]);
#pragma unroll
    for (int p = 0; p < 4; ++p) {
      half4v h, l;
      h.x = (_Float16)av[p].x; l.x = (_Float16)(av[p].x - (float)h.x);
      h.y = (_Float16)av[p].y; l.y = (_Float16)(av[p].y - (float)h.y);
      h.z = (_Float16)av[p].z; l.z = (_Float16)(av[p].z - (float)h.z);
      h.w = (_Float16)av[p].w; l.w = (_Float16)(av[p].w - (float)h.w);
      const int off = (ar + 32 * p) * 32 + ac;
      *(half4v*)&sAh[off] = h;
      *(half4v*)&sAl[off] = l;
    }
    __syncthreads();

    half8 ah[4], al[4], bh[4], bl[4];
#pragma unroll
    for (int i = 0; i < 4; ++i) {
      ah[i] = *(const half8*)&sAh[(mbase + i * 16 + fm) * 32 + fk];
      al[i] = *(const half8*)&sAl[(mbase + i * 16 + fm) * 32 + fk];
      bh[i] = *(const half8*)&sBh[(nbase + i * 16 + fm) * 32 + fk];
      bl[i] = *(const half8*)&sBl[(nbase + i * 16 + fm) * 32 + fk];
    }
#pragma unroll
    for (int i = 0; i < 4; ++i)
#pragma unroll
      for (int j = 0; j < 4; ++j) {
        acc[i][j] = __builtin_amdgcn_mfma_f32_16x16x32_f16(ah[i], bh[j], acc[i][j], 0, 0, 0);
        acc[i][j] = __builtin_amdgcn_mfma_f32_16x16x32_f16(ah[i], bl[j], acc[i][j], 0, 0, 0);
        acc[i][j] = __builtin_amdgcn_mfma_f32_16x16x32_f16(al[i], bh[j], acc[i][j], 0, 0, 0);
      }
  }

  const int cr = (lane >> 4) * 4;
#pragma unroll
  for (int i = 0; i < 4; ++i) {
    const int grow = bm + mbase + i * 16 + cr;
#pragma unroll
    for (int j = 0; j < 4; ++j) {
      const int gcol = bn + nbase + j * 16 + fm;
      const float bo = bias[gcol];
#pragma unroll
      for (int r = 0; r < 4; ++r)
        C[(size_t)(grow + r) * N + gcol] = acc[i][j][r] + bo;
    }
  }
}

// ---------------------------------------------------------------------------
// Fused conv(K)+fm, conv(V), partial-KV. Register-blocked outer product:
// lane owns 4d x 4e (d quarter-uniform b128 broadcast, e contiguous b128).
// Grid (64 bh, 16 chunks of 256 s). Deterministic partials.
// ---------------------------------------------------------------------------
__global__ __launch_bounds__(256) void kv_accum_conv(
    const float* __restrict__ Kg, const float* __restrict__ Vg,
    const float* __restrict__ kc_w, const float* __restrict__ kc_b,
    const float* __restrict__ vc_w, const float* __restrict__ vc_b,
    float* __restrict__ KVp, float* __restrict__ Ksp) {
  const int bh = blockIdx.x;
  const int b = bh >> 4, h = bh & 15;
  const int chunk = blockIdx.y;
  const int s0 = chunk * 256;
  const int t = threadIdx.x;
  const int w = t >> 6, lane = t & 63;
  __shared__ float Kr[34][64], Vr[34][64];
  __shared__ float Kc[32][64], Vc[32][64];
  __shared__ float kw0[64], kw1[64], kw2[64], kb_[64];
  __shared__ float vw0[64], vw1[64], vw2[64], vb_[64];

  if (t < 64) {
    kw0[t] = kc_w[t * 3 + 0]; kw1[t] = kc_w[t * 3 + 1]; kw2[t] = kc_w[t * 3 + 2];
    vw0[t] = vc_w[t * 3 + 0]; vw1[t] = vc_w[t * 3 + 1]; vw2[t] = vc_w[t * 3 + 2];
    kb_[t] = kc_b[t]; vb_[t] = vc_b[t];
  }

  const int d0 = w * 16 + (lane >> 4) * 4;   // quarter-uniform d quartet
  const int e0 = (lane & 15) * 4;            // contiguous e quartet
  float acc[4][4];
#pragma unroll
  for (int i = 0; i < 4; ++i)
#pragma unroll
    for (int j = 0; j < 4; ++j) acc[i][j] = 0.f;
  float4 ks = make_float4(0.f, 0.f, 0.f, 0.f);
  const size_t gbase = (size_t)b * SS * DM + h * HD;

  for (int c = 0; c < 256; c += 32) {
    __syncthreads();
    for (int idx = t; idx < 544; idx += 256) {
      const int row = idx >> 4, col = (idx & 15) * 4;
      const int s = s0 + c - 2 + row;
      float4 k4 = make_float4(0.f, 0.f, 0.f, 0.f);
      float4 v4 = make_float4(0.f, 0.f, 0.f, 0.f);
      if (s >= 0) {
        k4 = *(const float4*)&Kg[gbase + (size_t)s * DM + col];
        v4 = *(const float4*)&Vg[gbase + (size_t)s * DM + col];
      }
      *(float4*)&Kr[row][col] = k4;
      *(float4*)&Vr[row][col] = v4;
    }
    __syncthreads();
    for (int idx = t; idx < 2048; idx += 256) {
      const int row = idx >> 6, dd = idx & 63;
      float yk = kb_[dd] + kw0[dd] * Kr[row][dd] + kw1[dd] * Kr[row + 1][dd] +
                 kw2[dd] * Kr[row + 2][dd];
      Kc[row][dd] = (yk > 0.f) ? (yk + 1.f) : expf(yk);
      Vc[row][dd] = vb_[dd] + vw0[dd] * Vr[row][dd] + vw1[dd] * Vr[row + 1][dd] +
                    vw2[dd] * Vr[row + 2][dd];
    }
    __syncthreads();
#pragma unroll 2
    for (int ss = 0; ss < 32; ++ss) {
      const float4 k4 = *(const float4*)&Kc[ss][d0];
      const float4 v4 = *(const float4*)&Vc[ss][e0];
      ks.x += k4.x; ks.y += k4.y; ks.z += k4.z; ks.w += k4.w;
      const float kk[4] = {k4.x, k4.y, k4.z, k4.w};
      const float vv[4] = {v4.x, v4.y, v4.z, v4.w};
#pragma unroll
      for (int i = 0; i < 4; ++i)
#pragma unroll
        for (int j = 0; j < 4; ++j) acc[i][j] = fmaf(kk[i], vv[j], acc[i][j]);
    }
  }
  float* kvp = &KVp[((size_t)(bh * 16 + chunk)) * 4096];
#pragma unroll
  for (int i = 0; i < 4; ++i) {
    float4 o = make_float4(acc[i][0], acc[i][1], acc[i][2], acc[i][3]);
    *(float4*)&kvp[(d0 + i) * 64 + e0] = o;
  }
  if ((lane & 15) == 0) {
    float* kp = &Ksp[(bh * 16 + chunk) * 64 + d0];
    kp[0] = ks.x; kp[1] = ks.y; kp[2] = ks.z; kp[3] = ks.w;
  }
}

// Reduce 16 partials; Ksum gets +eps folded in.
__global__ __launch_bounds__(256) void kv_reduce(
    const float* __restrict__ KVp, const float* __restrict__ Ksp,
    float* __restrict__ KV, float* __restrict__ Ksum) {
  const int bh = blockIdx.x;
  const int t = threadIdx.x;
  for (int i = t; i < 4096; i += 256) {
    float s = 0.f;
#pragma unroll
    for (int c = 0; c < 16; ++c) s += KVp[((size_t)(bh * 16 + c)) * 4096 + i];
    KV[(size_t)bh * 4096 + i] = s;
  }
  if (t < 64) {
    float s = 1e-6f;
#pragma unroll
    for (int c = 0; c < 16; ++c) s += Ksp[(bh * 16 + c) * 64 + t];
    Ksum[bh * 64 + t] = s;
  }
}

// ---------------------------------------------------------------------------
// Fused conv(Q)+fm + attention apply, register-blocked. Lane owns 4s x 4e.
// Q stored transposed in LDS (QsT[d][s], pad 68). den computed in conv phase.
// Writes fp32 out (coalesced float4). Grid (64 bh, 64 chunks of 64 s).
// ---------------------------------------------------------------------------
__global__ __launch_bounds__(256) void attn_apply_conv(
    const float* __restrict__ Qg, const float* __restrict__ KV,
    const float* __restrict__ Ksum, const float* __restrict__ qc_w,
    const float* __restrict__ qc_b, float* __restrict__ Og) {
  const int bh = blockIdx.x;
  const int b = bh >> 4, h = bh & 15;
  const int s0 = blockIdx.y * 64;
  const int t = threadIdx.x;
  const int w = t >> 6, lane = t & 63;
  __shared__ float Qr[66][64];    // raw rows s0-2 .. s0+63
  __shared__ float QsT[64][68];   // conv'd+fm, transposed [d][s]
  __shared__ float KVs[64][64];
  __shared__ float pden[64][4];
  __shared__ float kse[64];
  __shared__ float qw0[64], qw1[64], qw2[64], qb_[64];
  const size_t gbase = (size_t)b * SS * DM + h * HD;

  for (int idx = t; idx < 1056; idx += 256) {  // 66 rows * 16 float4
    const int row = idx >> 4, col = (idx & 15) * 4;
    const int s = s0 - 2 + row;
    float4 q4 = make_float4(0.f, 0.f, 0.f, 0.f);
    if (s >= 0) q4 = *(const float4*)&Qg[gbase + (size_t)s * DM + col];
    *(float4*)&Qr[row][col] = q4;
  }
  for (int idx = t; idx < 1024; idx += 256) {  // 64 rows * 16 float4
    const int row = idx >> 4, col = (idx & 15) * 4;
    *(float4*)&KVs[row][col] = *(const float4*)&KV[(size_t)bh * 4096 + row * 64 + col];
  }
  if (t < 64) {
    kse[t] = Ksum[bh * 64 + t];  // eps already folded in
    qw0[t] = qc_w[t * 3 + 0]; qw1[t] = qc_w[t * 3 + 1]; qw2[t] = qc_w[t * 3 + 2];
    qb_[t] = qc_b[t];
  }
  __syncthreads();

  // conv + fm + den partials; write transposed
  {
    const int crow = t >> 2;            // 0..63
    const int db = (t & 3) * 16;        // d-block of 16
    float denp = 0.f;
#pragma unroll
    for (int q = 0; q < 4; ++q) {
      const float4 xm2 = *(const float4*)&Qr[crow][db + q * 4];
      const float4 xm1 = *(const float4*)&Qr[crow + 1][db + q * 4];
      const float4 xc0 = *(const float4*)&Qr[crow + 2][db + q * 4];
      const float a2[4] = {xm2.x, xm2.y, xm2.z, xm2.w};
      const float a1[4] = {xm1.x, xm1.y, xm1.z, xm1.w};
      const float a0[4] = {xc0.x, xc0.y, xc0.z, xc0.w};
#pragma unroll
      for (int e = 0; e < 4; ++e) {
        const int dd = db + q * 4 + e;
        float y = qb_[dd] + qw0[dd] * a2[e] + qw1[dd] * a1[e] + qw2[dd] * a0[e];
        y = (y > 0.f) ? (y + 1.f) : expf(y);
        denp = fmaf(y, kse[dd], denp);
        QsT[dd][crow] = y;
      }
    }
    pden[crow][t & 3] = denp;
  }
  __syncthreads();

  const int sl0 = w * 16 + (lane >> 4) * 4;  // quarter-uniform s quartet
  const int e0 = (lane & 15) * 4;            // contiguous e quartet
  float acc[4][4];
#pragma unroll
  for (int i = 0; i < 4; ++i)
#pragma unroll
    for (int j = 0; j < 4; ++j) acc[i][j] = 0.f;
#pragma unroll 2
  for (int d = 0; d < 64; ++d) {
    const float4 q4 = *(const float4*)&QsT[d][sl0];
    const float4 v4 = *(const float4*)&KVs[d][e0];
    const float qq[4] = {q4.x, q4.y, q4.z, q4.w};
    const float vv[4] = {v4.x, v4.y, v4.z, v4.w};
#pragma unroll
    for (int i = 0; i < 4; ++i)
#pragma unroll
      for (int j = 0; j < 4; ++j) acc[i][j] = fmaf(qq[i], vv[j], acc[i][j]);
  }
#pragma unroll
  for (int i = 0; i < 4; ++i) {
    const float4 pd = *(const float4*)&pden[sl0 + i][0];
    const float z = 1.0f / (pd.x + pd.y + pd.z + pd.w);
    float4 o = make_float4(acc[i][0] * z, acc[i][1] * z, acc[i][2] * z,
                           acc[i][3] * z);
    *(float4*)&Og[gbase + (size_t)(s0 + sl0 + i) * DM + e0] = o;
  }
}

// ---------------------------------------------------------------------------
extern "C" void kernel_launch(void* const* d_in, const int* in_sizes, int n_in,
                              void* d_out, int out_size, void* d_ws, size_t ws_size,
                              hipStream_t stream) {
  const float* query = (const float*)d_in[0];
  const float* key   = (const float*)d_in[1];
  const float* value = (const float*)d_in[2];
  const float* q_w = (const float*)d_in[3];
  const float* q_b = (const float*)d_in[4];
  const float* k_w = (const float*)d_in[5];
  const float* k_b = (const float*)d_in[6];
  const float* v_w = (const float*)d_in[7];
  const float* v_b = (const float*)d_in[8];
  const float* o_w = (const float*)d_in[9];
  const float* o_b = (const float*)d_in[10];
  const float* qc_w = (const float*)d_in[11];
  const float* qc_b = (const float*)d_in[12];
  const float* kc_w = (const float*)d_in[13];
  const float* kc_b = (const float*)d_in[14];
  const float* vc_w = (const float*)d_in[15];
  const float* vc_b = (const float*)d_in[16];
  float* out = (float*)d_out;

  // Workspace (~226 MB)
  float* ws = (float*)d_ws;
  float* buf0 = ws;                    // raw K proj -> attn fp32 out
  float* buf1 = ws + TSZ;              // raw V proj
  float* buf2 = ws + 2 * TSZ;          // raw Q proj
  _Float16* Whi = (_Float16*)(ws + 3 * TSZ);  // 4 x 2 MB (k,v,q,o)
  _Float16* Wlo = Whi + 4 * (1 << 20);
  float* KVp  = (float*)(Wlo + 4 * (1 << 20));   // 64*16*4096
  float* Ksp  = KVp + (size_t)64 * 16 * 4096;    // 64*16*64
  float* KV   = Ksp + 64 * 16 * 64;
  float* Ksum = KV + (size_t)64 * 4096;

  _Float16* WhiO = Whi + 3 * (1 << 20);
  _Float16* WloO = Wlo + 3 * (1 << 20);

  const int nW4 = DM * DM / 4;

  split_w4<<<dim3(nW4 / 256, 4), 256, 0, stream>>>(k_w, v_w, q_w, o_w, Whi, Wlo);

  qkv_gemm_rawA<<<dim3(DM / 128, NTOK / 128, 3), 256, 0, stream>>>(
      key, value, query, Whi, Wlo, k_b, v_b, q_b, buf0, buf1, buf2);

  kv_accum_conv<<<dim3(64, 16), 256, 0, stream>>>(buf0, buf1, kc_w, kc_b, vc_w,
                                                  vc_b, KVp, Ksp);
  kv_reduce<<<64, 256, 0, stream>>>(KVp, Ksp, KV, Ksum);

  // conv(Q)+fm + attention; writes fp32 into buf0 (dead after kv_accum)
  attn_apply_conv<<<dim3(64, 64), 256, 0, stream>>>(buf2, KV, Ksum, qc_w, qc_b,
                                                    buf0);

  o_gemm_rawA<<<dim3(DM / 128, NTOK / 128), 256, 0, stream>>>(buf0, WhiO, WloO,
                                                              o_b, out);
}